// Round 3
// baseline (9434.660 us; speedup 1.0000x reference)
//
#include <hip/hip_runtime.h>
#include <hip/hip_bf16.h>

// ---------------- constants ----------------
// B=32, N=8192, S1=512, S2=256, K=32
#define NB 32
#define NP 8192

// ---------- distance helpers (match numpy: no FMA contraction) ----------
__device__ __forceinline__ float dist3(float ax, float ay, float az,
                                       float bx, float by, float bz) {
#pragma clang fp contract(off)
  float dx = ax - bx, dy = ay - by, dz = az - bz;
  return dx * dx + dy * dy + dz * dz;
}
__device__ __forceinline__ float sumsq3(float x, float y, float z) {
#pragma clang fp contract(off)
  return x * x + y * y + z * z;
}
__device__ __forceinline__ float knndist(float qx, float qy, float qz, float qq,
                                         float cx, float cy, float cz) {
#pragma clang fp contract(off)
  float dot = qx * cx + qy * cy + qz * cz;
  float cc = cx * cx + cy * cy + cz * cz;
  return (qq - 2.0f * dot) + cc;
}

// ---------------- weight transpose: wT[d][O] = w[o][d] ----------------
__global__ void k_transpose(const float* __restrict__ w, float* __restrict__ wT,
                            int O, int Dd) {
  int i = blockIdx.x * 256 + threadIdx.x;
  if (i < O * Dd) {
    int o = i / Dd, d = i - o * Dd;
    wT[d * O + o] = w[i];
  }
}

// ---------------- stage1a: xyz + y1 = x * w1^T ----------------
__global__ __launch_bounds__(256) void k_s1a(const float* __restrict__ x,
                                             const float* __restrict__ w1,
                                             float* __restrict__ xyz,
                                             float* __restrict__ y1) {
  __shared__ float w1s[192];
  int t = threadIdx.x;
  if (t < 192) w1s[t] = w1[t];
  int gid = blockIdx.x * 256 + t;  // 0 .. B*N-1
  int b = gid >> 13, n = gid & (NP - 1);
  __syncthreads();
  const size_t xb = (size_t)b * 3 * NP;
  float x0 = x[xb + n], x1 = x[xb + NP + n], x2 = x[xb + 2 * NP + n];
  xyz[(size_t)gid * 3 + 0] = x0;
  xyz[(size_t)gid * 3 + 1] = x1;
  xyz[(size_t)gid * 3 + 2] = x2;
  float* yo = y1 + (size_t)gid * 64;
#pragma unroll
  for (int o = 0; o < 64; o += 4) {
    float4 v;
    v.x = x0 * w1s[(o + 0) * 3] + x1 * w1s[(o + 0) * 3 + 1] + x2 * w1s[(o + 0) * 3 + 2];
    v.y = x0 * w1s[(o + 1) * 3] + x1 * w1s[(o + 1) * 3 + 1] + x2 * w1s[(o + 1) * 3 + 2];
    v.z = x0 * w1s[(o + 2) * 3] + x1 * w1s[(o + 2) * 3 + 1] + x2 * w1s[(o + 2) * 3 + 2];
    v.w = x0 * w1s[(o + 3) * 3] + x1 * w1s[(o + 3) * 3 + 1] + x2 * w1s[(o + 3) * 3 + 2];
    *(float4*)&yo[o] = v;
  }
}

// ---------------- per-channel (C=64) sum/sumsq over [M][64], float4 ----------------
__global__ __launch_bounds__(256) void k_colstats(const float* __restrict__ buf,
                                                  size_t ME4, float* __restrict__ part) {
  __shared__ float red[128];
  int t = threadIdx.x;
  if (t < 128) red[t] = 0.f;
  float s[4] = {0.f, 0.f, 0.f, 0.f}, q[4] = {0.f, 0.f, 0.f, 0.f};
  size_t stride = (size_t)gridDim.x * 256;  // *4 floats: multiple of 64 -> c0 constant
  size_t i0 = (size_t)blockIdx.x * 256 + t;
  int c0 = (int)((i0 * 4) & 63);
  for (size_t i = i0; i < ME4; i += stride) {
    float4 v = ((const float4*)buf)[i];
    s[0] += v.x; q[0] += v.x * v.x;
    s[1] += v.y; q[1] += v.y * v.y;
    s[2] += v.z; q[2] += v.z * v.z;
    s[3] += v.w; q[3] += v.w * v.w;
  }
  __syncthreads();
#pragma unroll
  for (int j = 0; j < 4; ++j) {
    atomicAdd(&red[c0 + j], s[j]);
    atomicAdd(&red[64 + c0 + j], q[j]);
  }
  __syncthreads();
  if (t < 128) atomicAdd(&part[(size_t)(blockIdx.x & 63) * 128 + t], red[t]);
}

// ---------------- BN finalize: partials[64][2*C] -> scale/shift[2*C] ----------------
__global__ void k_bnfinal(const float* __restrict__ part, const float* __restrict__ gamma,
                          const float* __restrict__ beta, float invcnt, int C,
                          float* __restrict__ sc) {
  int c = threadIdx.x;
  if (c >= C) return;
  float s = 0.f, q = 0.f;
  for (int p = 0; p < 64; ++p) {
    s += part[(size_t)p * 2 * C + c];
    q += part[(size_t)p * 2 * C + C + c];
  }
  float mean = s * invcnt;
  float var = fmaxf(q * invcnt - mean * mean, 0.f);
  float scale = gamma[c] * rsqrtf(var + 1e-5f);
  sc[c] = scale;
  sc[C + c] = beta[c] - mean * scale;
}

// ---------------- stage1c: y2 = w2 * relu(bn(y1)), 64-point tiles (in-place safe) ----
__global__ __launch_bounds__(256) void k_s1c(const float* __restrict__ y1,
                                             const float* __restrict__ w2T,
                                             const float* __restrict__ sc1,
                                             float* __restrict__ y2) {
  __shared__ __align__(16) float f1[64 * 65];
  __shared__ __align__(16) float w2s[64 * 64];
  __shared__ float scs[128];
  int t = threadIdx.x;
  if (t < 128) scs[t] = sc1[t];
  for (int i = t; i < 4096; i += 256) w2s[i] = w2T[i];
  size_t base = (size_t)blockIdx.x * 4096;
  __syncthreads();
  for (int i = t; i < 4096; i += 256) {
    int p = i >> 6, c = i & 63;
    float v = y1[base + i];
    v = fmaxf(0.f, v * scs[c] + scs[64 + c]);
    f1[p * 65 + c] = v;
  }
  __syncthreads();
  int pq = t & 15, oq = t >> 4;
  int p0 = pq * 4, o0 = oq * 4;
  float ac[4][4] = {};
  for (int c = 0; c < 64; ++c) {
    float4 wv = *(const float4*)&w2s[c * 64 + o0];
    float a0 = f1[(p0 + 0) * 65 + c];
    float a1 = f1[(p0 + 1) * 65 + c];
    float a2 = f1[(p0 + 2) * 65 + c];
    float a3 = f1[(p0 + 3) * 65 + c];
    ac[0][0] += a0 * wv.x; ac[0][1] += a0 * wv.y; ac[0][2] += a0 * wv.z; ac[0][3] += a0 * wv.w;
    ac[1][0] += a1 * wv.x; ac[1][1] += a1 * wv.y; ac[1][2] += a1 * wv.z; ac[1][3] += a1 * wv.w;
    ac[2][0] += a2 * wv.x; ac[2][1] += a2 * wv.y; ac[2][2] += a2 * wv.z; ac[2][3] += a2 * wv.w;
    ac[3][0] += a3 * wv.x; ac[3][1] += a3 * wv.y; ac[3][2] += a3 * wv.z; ac[3][3] += a3 * wv.w;
  }
#pragma unroll
  for (int i2 = 0; i2 < 4; ++i2) {
    float4 v = {ac[i2][0], ac[i2][1], ac[i2][2], ac[i2][3]};
    *(float4*)&y2[base + (size_t)(p0 + i2) * 64 + o0] = v;
  }
}

// ---------------- stage1e: in-place bn+relu over [M][64] ----------------
__global__ __launch_bounds__(256) void k_s1e(float* __restrict__ y2,
                                             const float* __restrict__ sc2, size_t ME4) {
  __shared__ float scs[128];
  int t = threadIdx.x;
  if (t < 128) scs[t] = sc2[t];
  __syncthreads();
  size_t stride = (size_t)gridDim.x * 256;
  for (size_t i = (size_t)blockIdx.x * 256 + t; i < ME4; i += stride) {
    float4 v = ((float4*)y2)[i];
    int c0 = (int)((i * 4) & 63);
    v.x = fmaxf(0.f, v.x * scs[c0 + 0] + scs[64 + c0 + 0]);
    v.y = fmaxf(0.f, v.y * scs[c0 + 1] + scs[64 + c0 + 1]);
    v.z = fmaxf(0.f, v.z * scs[c0 + 2] + scs[64 + c0 + 2]);
    v.w = fmaxf(0.f, v.w * scs[c0 + 3] + scs[64 + c0 + 3]);
    ((float4*)y2)[i] = v;
  }
}

// ---------------- FPS: one block per batch ----------------
template <int PPT>
__global__ void k_fps(const float* __restrict__ xyz, int N, int S,
                      int* __restrict__ fidx, float* __restrict__ sxyz) {
  const int T = blockDim.x;  // N / PPT
  const int t = threadIdx.x;
  const int b = blockIdx.x;
  const float* base = xyz + (size_t)b * N * 3;
  float cx[PPT], cy[PPT], cz[PPT], dist[PPT];
#pragma unroll
  for (int j = 0; j < PPT; ++j) {
    int n = t + j * T;
    cx[j] = base[(size_t)n * 3 + 0];
    cy[j] = base[(size_t)n * 3 + 1];
    cz[j] = base[(size_t)n * 3 + 2];
    dist[j] = 1e10f;
  }
  __shared__ float sx, sy, sz;
  __shared__ float wv[16];
  __shared__ int wi[16];
  if (t == 0) {
    fidx[(size_t)b * S] = 0;
    float gx = base[0], gy = base[1], gz = base[2];
    sx = gx; sy = gy; sz = gz;
    sxyz[((size_t)b * S) * 3 + 0] = gx;
    sxyz[((size_t)b * S) * 3 + 1] = gy;
    sxyz[((size_t)b * S) * 3 + 2] = gz;
  }
  __syncthreads();
  for (int it = 1; it < S; ++it) {
    float px = sx, py = sy, pz = sz;
    float bv = -1.0f;
    int bi = 0x7FFFFFFF;
#pragma unroll
    for (int j = 0; j < PPT; ++j) {
      float d = dist3(cx[j], cy[j], cz[j], px, py, pz);
      float dj = fminf(dist[j], d);
      dist[j] = dj;
      if (dj > bv) { bv = dj; bi = t + j * T; }  // j increasing -> first idx in thread
    }
#pragma unroll
    for (int off = 32; off > 0; off >>= 1) {
      float ov = __shfl_xor(bv, off);
      int oi = __shfl_xor(bi, off);
      if (ov > bv || (ov == bv && oi < bi)) { bv = ov; bi = oi; }
    }
    int wid = t >> 6;
    if ((t & 63) == 0) { wv[wid] = bv; wi[wid] = bi; }
    __syncthreads();
    if (t == 0) {
      int nw = T >> 6;
      float v = wv[0];
      int ii = wi[0];
      for (int w2_ = 1; w2_ < nw; ++w2_)
        if (wv[w2_] > v || (wv[w2_] == v && wi[w2_] < ii)) { v = wv[w2_]; ii = wi[w2_]; }
      fidx[(size_t)b * S + it] = ii;
      float gx = base[(size_t)ii * 3 + 0];
      float gy = base[(size_t)ii * 3 + 1];
      float gz = base[(size_t)ii * 3 + 2];
      sx = gx; sy = gy; sz = gz;
      sxyz[((size_t)b * S + it) * 3 + 0] = gx;
      sxyz[((size_t)b * S + it) * 3 + 1] = gy;
      sxyz[((size_t)b * S + it) * 3 + 2] = gz;
    }
    __syncthreads();
  }
}

// ---------------- KNN top-32 (iterative argmin) ----------------
template <int NMAX>
__global__ __launch_bounds__(256) void k_knn(const float* __restrict__ cxyz,
                                             const float* __restrict__ qxyz, int N, int S,
                                             int* __restrict__ knn) {
  __shared__ float dist[NMAX];
  __shared__ float wv[4];
  __shared__ int wi[4];
  const int t = threadIdx.x;
  const int bs = blockIdx.x;
  const int b = bs / S;
  float qx = qxyz[(size_t)bs * 3 + 0];
  float qy = qxyz[(size_t)bs * 3 + 1];
  float qz = qxyz[(size_t)bs * 3 + 2];
  float qq = sumsq3(qx, qy, qz);
  const float* cb = cxyz + (size_t)b * N * 3;
  for (int n = t; n < N; n += 256)
    dist[n] = knndist(qx, qy, qz, qq, cb[(size_t)n * 3], cb[(size_t)n * 3 + 1], cb[(size_t)n * 3 + 2]);
  __syncthreads();
  for (int r = 0; r < 32; ++r) {
    float bvv = 3.0e38f;
    int bii = 0x7FFFFFFF;
    for (int n = t; n < N; n += 256) {
      float d = dist[n];
      if (d < bvv) { bvv = d; bii = n; }
    }
#pragma unroll
    for (int off = 32; off > 0; off >>= 1) {
      float ov = __shfl_xor(bvv, off);
      int oi = __shfl_xor(bii, off);
      if (ov < bvv || (ov == bvv && oi < bii)) { bvv = ov; bii = oi; }
    }
    int wid = t >> 6;
    if ((t & 63) == 0) { wv[wid] = bvv; wi[wid] = bii; }
    __syncthreads();
    if (t == 0) {
      float v = wv[0];
      int ii = wi[0];
      for (int w2_ = 1; w2_ < 4; ++w2_)
        if (wv[w2_] < v || (wv[w2_] == v && wi[w2_] < ii)) { v = wv[w2_]; ii = wi[w2_]; }
      knn[(size_t)bs * 32 + r] = ii;
      dist[ii] = 3.0e38f;
    }
    __syncthreads();
  }
}

// ---------------- shared helpers for SG GEMMs ----------------
__device__ __forceinline__ int swzcol(int d, int k) {
  return (k & 3) | ((((unsigned(k) >> 2) ^ (unsigned(d) >> 2)) & 7) << 2);
}

// X: [D2][32] swizzled LDS; WT: [D2][O] global; wch: [32][O] LDS staging.
template <int D2, int O, int NT>
__device__ __forceinline__ void sg_gemm(const float* __restrict__ X,
                                        const float* __restrict__ WT,
                                        float* __restrict__ wch, int t, int o0, int kq,
                                        float (&ac)[4][4]) {
  constexpr int K = 32;
#pragma unroll
  for (int i2 = 0; i2 < 4; ++i2)
#pragma unroll
    for (int j = 0; j < 4; ++j) ac[i2][j] = 0.f;
  for (int dc = 0; dc < D2; dc += 32) {
    __syncthreads();
    for (int i = t; i < 32 * O; i += NT) wch[i] = WT[(size_t)dc * O + i];
    __syncthreads();
#pragma unroll 8
    for (int dd = 0; dd < 32; ++dd) {
      int d = dc + dd;
      const float4 wv = *(const float4*)&wch[dd * O + o0];
      const float4 av = *(const float4*)&X[d * K + ((kq ^ ((d >> 2) & 7)) << 2)];
      ac[0][0] += wv.x * av.x; ac[0][1] += wv.x * av.y; ac[0][2] += wv.x * av.z; ac[0][3] += wv.x * av.w;
      ac[1][0] += wv.y * av.x; ac[1][1] += wv.y * av.y; ac[1][2] += wv.y * av.z; ac[1][3] += wv.y * av.w;
      ac[2][0] += wv.z * av.x; ac[2][1] += wv.z * av.y; ac[2][2] += wv.z * av.z; ac[2][3] += wv.z * av.w;
      ac[3][0] += wv.w * av.x; ac[3][1] += wv.w * av.y; ac[3][2] += wv.w * av.z; ac[3][3] += wv.w * av.w;
    }
  }
}

// ---------------- materialized path: pass A (gather + GEMM A -> yA + statsA) --------
template <int D, int NT>
__global__ __launch_bounds__(NT) void k_sgA(const float* __restrict__ f, int Nf, int S,
                                            const int* __restrict__ fpsidx,
                                            const int* __restrict__ knn,
                                            const float* __restrict__ waT,
                                            float* __restrict__ yA,
                                            float* __restrict__ statsOut) {
  constexpr int D2 = 2 * D, O = D2, K = 32;
  __shared__ __align__(16) float agg[D2 * K];
  __shared__ __align__(16) float wch[32 * O];
  __shared__ float fq[D];
  __shared__ int nidx[K];
  __shared__ float red[2 * O];
  const int t = threadIdx.x;
  const int bs = blockIdx.x;
  const int b = bs / S;
  const int qi = fpsidx[bs];
  if (t < K) nidx[t] = knn[(size_t)bs * K + t];
  for (int i = t; i < D; i += NT) fq[i] = f[((size_t)b * Nf + qi) * D + i];
  __syncthreads();
  for (int idx = t; idx < K * D; idx += NT) {
    int k = idx / D, dd = idx - k * D;
    float v = f[((size_t)b * Nf + nidx[k]) * D + dd];
    float q = fq[dd];
    agg[dd * K + swzcol(dd, k)] = v - q;
    agg[(D + dd) * K + swzcol(D + dd, k)] = q;
  }
  const int oq = t >> 3, kq = t & 7;  // NT == 2*O guaranteed (256/128, 512/256)
  const int o0 = oq * 4, k0 = kq * 4;
  float acc[4][4];
  sg_gemm<D2, O, NT>(agg, waT, wch, t, o0, kq, acc);
  // write yA tile [bs][O][K]
  float* yt = yA + (size_t)bs * O * K;
#pragma unroll
  for (int i2 = 0; i2 < 4; ++i2) {
    float4 v = {acc[i2][0], acc[i2][1], acc[i2][2], acc[i2][3]};
    *(float4*)&yt[(size_t)(o0 + i2) * K + k0] = v;
  }
  // stats
  for (int i = t; i < 2 * O; i += NT) red[i] = 0.f;
  __syncthreads();
#pragma unroll
  for (int i2 = 0; i2 < 4; ++i2) {
    float sv = 0.f, sq = 0.f;
#pragma unroll
    for (int j = 0; j < 4; ++j) {
      float v = acc[i2][j];
      sv += v;
      sq += v * v;
    }
    atomicAdd(&red[o0 + i2], sv);
    atomicAdd(&red[O + o0 + i2], sq);
  }
  __syncthreads();
  float* slot = statsOut + (size_t)(bs & 63) * (2 * O);
  for (int i = t; i < 2 * O; i += NT) atomicAdd(&slot[i], red[i]);
}

// ------- materialized path: pass B (bnA+relu on yA -> GEMM B -> yB in-place + statsB)
template <int D, int NT>
__global__ __launch_bounds__(NT) void k_sgB(float* __restrict__ ybuf,
                                            const float* __restrict__ wbT,
                                            const float* __restrict__ bnA,
                                            float* __restrict__ statsOut) {
  constexpr int D2 = 2 * D, O = D2, K = 32;
  __shared__ __align__(16) float zA[D2 * K];
  __shared__ __align__(16) float wch[32 * O];
  __shared__ float scb[2 * O];
  __shared__ float red[2 * O];
  const int t = threadIdx.x;
  const int bs = blockIdx.x;
  for (int i = t; i < 2 * O; i += NT) scb[i] = bnA[i];
  __syncthreads();
  float* yt = ybuf + (size_t)bs * O * K;
  for (int idx = t; idx < O * K; idx += NT) {
    int o = idx >> 5, k = idx & 31;
    float v = yt[idx];
    float z = fmaxf(0.f, v * scb[o] + scb[O + o]);
    zA[o * K + swzcol(o, k)] = z;
  }
  const int oq = t >> 3, kq = t & 7;
  const int o0 = oq * 4, k0 = kq * 4;
  float acc[4][4];
  sg_gemm<D2, O, NT>(zA, wbT, wch, t, o0, kq, acc);  // first barrier covers zA writes
  // write yB tile in-place (all global reads of yt happened before first barrier)
#pragma unroll
  for (int i2 = 0; i2 < 4; ++i2) {
    float4 v = {acc[i2][0], acc[i2][1], acc[i2][2], acc[i2][3]};
    *(float4*)&yt[(size_t)(o0 + i2) * K + k0] = v;
  }
  // stats
  for (int i = t; i < 2 * O; i += NT) red[i] = 0.f;
  __syncthreads();
#pragma unroll
  for (int i2 = 0; i2 < 4; ++i2) {
    float sv = 0.f, sq = 0.f;
#pragma unroll
    for (int j = 0; j < 4; ++j) {
      float v = acc[i2][j];
      sv += v;
      sq += v * v;
    }
    atomicAdd(&red[o0 + i2], sv);
    atomicAdd(&red[O + o0 + i2], sq);
  }
  __syncthreads();
  float* slot = statsOut + (size_t)(bs & 63) * (2 * O);
  for (int i = t; i < 2 * O; i += NT) atomicAdd(&slot[i], red[i]);
}

// ------- materialized path: pass C (bnB+relu+maxpool over K -> out) ----------------
template <int O>
__global__ __launch_bounds__(256) void k_sgC(const float* __restrict__ ybuf,
                                             const float* __restrict__ bnB, int S,
                                             float* __restrict__ out, int finalOut) {
  constexpr int K = 32;
  __shared__ float scb[2 * O];
  const int t = threadIdx.x;
  const int bs = blockIdx.x;
  const int b = bs / S, s = bs - b * S;
  for (int i = t; i < 2 * O; i += 256) scb[i] = bnB[i];
  __syncthreads();
  const float* yt = ybuf + (size_t)bs * O * K;
  for (int i4 = t; i4 < O * 8; i4 += 256) {
    int o = i4 >> 3, j = i4 & 7;
    float4 v = *(const float4*)&yt[(size_t)o * K + j * 4];
    float sB = scb[o], tB = scb[O + o];
    float m = fmaxf(0.f, v.x * sB + tB);
    m = fmaxf(m, fmaxf(0.f, v.y * sB + tB));
    m = fmaxf(m, fmaxf(0.f, v.z * sB + tB));
    m = fmaxf(m, fmaxf(0.f, v.w * sB + tB));
#pragma unroll
    for (int off = 1; off < 8; off <<= 1) m = fmaxf(m, __shfl_xor(m, off));
    if (j == 0) {
      if (finalOut) out[((size_t)b * O + o) * S + s] = m;
      else out[(size_t)bs * O + o] = m;
    }
  }
}

// ---------------- fallback 3-pass SG kernel (recompute; used if ws too small) ------
template <int D, int PASS, int NT>
__global__ __launch_bounds__(NT) void k_sg(const float* __restrict__ f, int Nf, int S,
                                           const int* __restrict__ fpsidx,
                                           const int* __restrict__ knn,
                                           const float* __restrict__ waT,
                                           const float* __restrict__ wbT,
                                           const float* __restrict__ bnA,
                                           const float* __restrict__ bnB,
                                           float* __restrict__ statsOut,
                                           float* __restrict__ out, int finalOut) {
  constexpr int D2 = 2 * D, O = D2, K = 32;
  __shared__ __align__(16) float agg[D2 * K];
  __shared__ __align__(16) float wch[32 * O];
  __shared__ float fq[D];
  __shared__ int nidx[K];
  __shared__ __align__(16) float zA[(PASS >= 1) ? D2 * K : 1];
  __shared__ float red[2 * O];
  const int t = threadIdx.x;
  const int bs = blockIdx.x;
  const int b = bs / S, s = bs - b * S;
  const int qi = fpsidx[bs];
  if (t < K) nidx[t] = knn[(size_t)bs * K + t];
  for (int i = t; i < D; i += NT) fq[i] = f[((size_t)b * Nf + qi) * D + i];
  __syncthreads();
  for (int idx = t; idx < K * D; idx += NT) {
    int k = idx / D, dd = idx - k * D;
    float v = f[((size_t)b * Nf + nidx[k]) * D + dd];
    float q = fq[dd];
    agg[dd * K + swzcol(dd, k)] = v - q;
    agg[(D + dd) * K + swzcol(D + dd, k)] = q;
  }
  const int oq = t >> 3, kq = t & 7;
  const int o0 = oq * 4, k0 = kq * 4;
  float acc[4][4];
  sg_gemm<D2, O, NT>(agg, waT, wch, t, o0, kq, acc);

  if constexpr (PASS == 0) {
    for (int i = t; i < 2 * O; i += NT) red[i] = 0.f;
    __syncthreads();
#pragma unroll
    for (int i2 = 0; i2 < 4; ++i2) {
      float sv = 0.f, sq = 0.f;
#pragma unroll
      for (int j = 0; j < 4; ++j) {
        float v = acc[i2][j];
        sv += v;
        sq += v * v;
      }
      atomicAdd(&red[o0 + i2], sv);
      atomicAdd(&red[O + o0 + i2], sq);
    }
    __syncthreads();
    float* slot = statsOut + (size_t)(bs & 63) * (2 * O);
    for (int i = t; i < 2 * O; i += NT) atomicAdd(&slot[i], red[i]);
    return;
  } else {
#pragma unroll
    for (int i2 = 0; i2 < 4; ++i2) {
      float sA = bnA[o0 + i2], tA = bnA[O + o0 + i2];
#pragma unroll
      for (int j = 0; j < 4; ++j) {
        float z = fmaxf(0.f, acc[i2][j] * sA + tA);
        zA[(o0 + i2) * K + swzcol(o0 + i2, k0 + j)] = z;
      }
    }
    float acc2[4][4];
    sg_gemm<D2, O, NT>(zA, wbT, wch, t, o0, kq, acc2);

    if constexpr (PASS == 1) {
      for (int i = t; i < 2 * O; i += NT) red[i] = 0.f;
      __syncthreads();
#pragma unroll
      for (int i2 = 0; i2 < 4; ++i2) {
        float sv = 0.f, sq = 0.f;
#pragma unroll
        for (int j = 0; j < 4; ++j) {
          float v = acc2[i2][j];
          sv += v;
          sq += v * v;
        }
        atomicAdd(&red[o0 + i2], sv);
        atomicAdd(&red[O + o0 + i2], sq);
      }
      __syncthreads();
      float* slot = statsOut + (size_t)(bs & 63) * (2 * O);
      for (int i = t; i < 2 * O; i += NT) atomicAdd(&slot[i], red[i]);
      return;
    } else {
      for (int i = t; i < O; i += NT) red[i] = 0.f;
      __syncthreads();
#pragma unroll
      for (int i2 = 0; i2 < 4; ++i2) {
        float sB = bnB[o0 + i2], tB = bnB[O + o0 + i2];
        float m = 0.f;
#pragma unroll
        for (int j = 0; j < 4; ++j) m = fmaxf(m, fmaxf(0.f, acc2[i2][j] * sB + tB));
        atomicMax((int*)&red[o0 + i2], __float_as_int(m));  // relu output >= 0
      }
      __syncthreads();
      if (finalOut) {
        for (int i = t; i < O; i += NT) out[((size_t)b * O + i) * S + s] = red[i];
      } else {
        for (int i = t; i < O; i += NT) out[(size_t)bs * O + i] = red[i];
      }
    }
  }
}

// ---------------- host launch ----------------
extern "C" void kernel_launch(void* const* d_in, const int* in_sizes, int n_in,
                              void* d_out, int out_size, void* d_ws, size_t ws_size,
                              hipStream_t stream) {
  (void)in_sizes; (void)n_in; (void)out_size;
  const float* x    = (const float*)d_in[0];
  const float* w1   = (const float*)d_in[1];
  const float* g1   = (const float*)d_in[2];
  const float* b1   = (const float*)d_in[3];
  const float* w2   = (const float*)d_in[4];
  const float* g2   = (const float*)d_in[5];
  const float* b2   = (const float*)d_in[6];
  const float* s1wa = (const float*)d_in[7];
  const float* s1ga = (const float*)d_in[8];
  const float* s1ba = (const float*)d_in[9];
  const float* s1wb = (const float*)d_in[10];
  const float* s1gb = (const float*)d_in[11];
  const float* s1bb = (const float*)d_in[12];
  const float* s2wa = (const float*)d_in[13];
  const float* s2ga = (const float*)d_in[14];
  const float* s2ba = (const float*)d_in[15];
  const float* s2wb = (const float*)d_in[16];
  const float* s2gb = (const float*)d_in[17];
  const float* s2bb = (const float*)d_in[18];
  float* out = (float*)d_out;

  char* wsp = (char*)d_ws;
  size_t off = 0;
  auto alloc = [&](size_t floats) {
    void* p = wsp + off;
    off += ((floats * 4 + 255) & ~(size_t)255);
    return p;
  };
  float* xyz  = (float*)alloc(786432);     // [B][N][3]
  float* y1   = (float*)alloc(16777216);   // [B*N][64] conv1 raw -> conv2 in-place -> features
  float* y2f  = y1;                        // alias: k_s1c is tile-in-LDS then overwrite (safe)
  float* f1f  = (float*)alloc(2097152);    // [B][S1][128]
  float* xyz1 = (float*)alloc(49152);      // [B][S1][3]
  float* xyz2 = (float*)alloc(24576);      // [B][S2][3]
  int* fi1    = (int*)alloc(16384);        // [B][S1]
  int* fi2    = (int*)alloc(8192);         // [B][S2]
  int* kn1    = (int*)alloc(524288);       // [B][S1][32]
  int* kn2    = (int*)alloc(262144);       // [B][S2][32]
  float* w2T  = (float*)alloc(4096);
  float* waT1 = (float*)alloc(16384);
  float* wbT1 = (float*)alloc(16384);
  float* waT2 = (float*)alloc(65536);
  float* wbT2 = (float*)alloc(65536);
  float* stats = (float*)alloc(116480);
  float* part_s1 = stats;                  // [64][128]
  float* part_s2 = stats + 8192;
  float* partA1  = stats + 16384;          // [64][256]
  float* partB1  = stats + 32768;
  float* partA2  = stats + 49152;          // [64][512]
  float* partB2  = stats + 81920;
  float* sc1  = stats + 114688;            // [2*64]
  float* sc2  = sc1 + 128;
  float* bnA1 = sc2 + 128;                 // [2*128]
  float* bnB1 = bnA1 + 256;
  float* bnA2 = bnB1 + 256;                // [2*256]
  float* bnB2 = bnA2 + 512;
  // big materialization buffer: max(16384*128*32, 8192*256*32) = 67,108,864 floats
  float* ybuf = (float*)alloc(67108864);
  const bool useMat = (off <= ws_size);    // constant per-harness -> graph-capture safe

  hipMemsetAsync(stats, 0, (size_t)114688 * 4, stream);

  // weight transposes
  k_transpose<<<(64 * 64 + 255) / 256, 256, 0, stream>>>(w2, w2T, 64, 64);
  k_transpose<<<(128 * 128 + 255) / 256, 256, 0, stream>>>(s1wa, waT1, 128, 128);
  k_transpose<<<(128 * 128 + 255) / 256, 256, 0, stream>>>(s1wb, wbT1, 128, 128);
  k_transpose<<<(256 * 256 + 255) / 256, 256, 0, stream>>>(s2wa, waT2, 256, 256);
  k_transpose<<<(256 * 256 + 255) / 256, 256, 0, stream>>>(s2wb, wbT2, 256, 256);

  const size_t MN = (size_t)NB * NP;  // 262144
  // stage 1
  k_s1a<<<(int)(MN / 256), 256, 0, stream>>>(x, w1, xyz, y1);
  k_colstats<<<1024, 256, 0, stream>>>(y1, MN * 16, part_s1);
  k_bnfinal<<<1, 64, 0, stream>>>(part_s1, g1, b1, 1.f / (float)MN, 64, sc1);
  k_s1c<<<(int)(MN / 64), 256, 0, stream>>>(y1, w2T, sc1, y2f);
  k_colstats<<<1024, 256, 0, stream>>>(y2f, MN * 16, part_s2);
  k_bnfinal<<<1, 64, 0, stream>>>(part_s2, g2, b2, 1.f / (float)MN, 64, sc2);
  k_s1e<<<2048, 256, 0, stream>>>(y2f, sc2, MN * 16);

  // sampling/grouping indices
  k_fps<8><<<NB, 1024, 0, stream>>>(xyz, NP, 512, fi1, xyz1);
  k_knn<8192><<<NB * 512, 256, 0, stream>>>(xyz, xyz1, NP, 512, kn1);

  const float icA1 = 1.f / (32.f * 512.f * 32.f);
  const float icA2 = 1.f / (32.f * 256.f * 32.f);

  if (useMat) {
    // ---- SG block 1 (materialized: A once, B once) ----
    k_sgA<64, 256><<<NB * 512, 256, 0, stream>>>(y2f, NP, 512, fi1, kn1, waT1, ybuf, partA1);
    k_bnfinal<<<1, 128, 0, stream>>>(partA1, s1ga, s1ba, icA1, 128, bnA1);
    k_sgB<64, 256><<<NB * 512, 256, 0, stream>>>(ybuf, wbT1, bnA1, partB1);
    k_bnfinal<<<1, 128, 0, stream>>>(partB1, s1gb, s1bb, icA1, 128, bnB1);
    k_sgC<128><<<NB * 512, 256, 0, stream>>>(ybuf, bnB1, 512, f1f, 0);

    k_fps<2><<<NB, 256, 0, stream>>>(xyz1, 512, 256, fi2, xyz2);
    k_knn<512><<<NB * 256, 256, 0, stream>>>(xyz1, xyz2, 512, 256, kn2);

    // ---- SG block 2 ----
    k_sgA<128, 512><<<NB * 256, 512, 0, stream>>>(f1f, 512, 256, fi2, kn2, waT2, ybuf, partA2);
    k_bnfinal<<<1, 256, 0, stream>>>(partA2, s2ga, s2ba, icA2, 256, bnA2);
    k_sgB<128, 512><<<NB * 256, 512, 0, stream>>>(ybuf, wbT2, bnA2, partB2);
    k_bnfinal<<<1, 256, 0, stream>>>(partB2, s2gb, s2bb, icA2, 256, bnB2);
    k_sgC<256><<<NB * 256, 256, 0, stream>>>(ybuf, bnB2, 256, out, 1);
  } else {
    // ---- fallback: original 3-pass recompute ----
    k_sg<64, 0, 256><<<NB * 512, 256, 0, stream>>>(y2f, NP, 512, fi1, kn1, waT1, wbT1,
                                                   nullptr, nullptr, partA1, nullptr, 0);
    k_bnfinal<<<1, 128, 0, stream>>>(partA1, s1ga, s1ba, icA1, 128, bnA1);
    k_sg<64, 1, 256><<<NB * 512, 256, 0, stream>>>(y2f, NP, 512, fi1, kn1, waT1, wbT1,
                                                   bnA1, nullptr, partB1, nullptr, 0);
    k_bnfinal<<<1, 128, 0, stream>>>(partB1, s1gb, s1bb, icA1, 128, bnB1);
    k_sg<64, 2, 256><<<NB * 512, 256, 0, stream>>>(y2f, NP, 512, fi1, kn1, waT1, wbT1,
                                                   bnA1, bnB1, nullptr, f1f, 0);

    k_fps<2><<<NB, 256, 0, stream>>>(xyz1, 512, 256, fi2, xyz2);
    k_knn<512><<<NB * 256, 256, 0, stream>>>(xyz1, xyz2, 512, 256, kn2);

    k_sg<128, 0, 512><<<NB * 256, 512, 0, stream>>>(f1f, 512, 256, fi2, kn2, waT2, wbT2,
                                                    nullptr, nullptr, partA2, nullptr, 0);
    k_bnfinal<<<1, 256, 0, stream>>>(partA2, s2ga, s2ba, icA2, 256, bnA2);
    k_sg<128, 1, 512><<<NB * 256, 512, 0, stream>>>(f1f, 512, 256, fi2, kn2, waT2, wbT2,
                                                    bnA2, nullptr, partB2, nullptr, 0);
    k_bnfinal<<<1, 256, 0, stream>>>(partB2, s2gb, s2bb, icA2, 256, bnB2);
    k_sg<128, 2, 512><<<NB * 256, 512, 0, stream>>>(f1f, 512, 256, fi2, kn2, waT2, wbT2,
                                                    bnA2, bnB2, nullptr, out, 1);
  }
}

// Round 4
// 5996.252 us; speedup vs baseline: 1.5734x; 1.5734x over previous
//
#include <hip/hip_runtime.h>
#include <hip/hip_bf16.h>

// ---------------- constants ----------------
// B=32, N=8192, S1=512, S2=256, K=32
#define NB 32
#define NP 8192

// ---------- distance helpers (match numpy: no FMA contraction) ----------
__device__ __forceinline__ float dist3(float ax, float ay, float az,
                                       float bx, float by, float bz) {
#pragma clang fp contract(off)
  float dx = ax - bx, dy = ay - by, dz = az - bz;
  return dx * dx + dy * dy + dz * dz;
}
__device__ __forceinline__ float sumsq3(float x, float y, float z) {
#pragma clang fp contract(off)
  return x * x + y * y + z * z;
}
__device__ __forceinline__ float knndist(float qx, float qy, float qz, float qq,
                                         float cx, float cy, float cz) {
#pragma clang fp contract(off)
  float dot = qx * cx + qy * cy + qz * cz;
  float cc = cx * cx + cy * cy + cz * cz;
  return (qq - 2.0f * dot) + cc;
}

// ---------------- weight transpose: wT[d][O] = w[o][d] ----------------
__global__ void k_transpose(const float* __restrict__ w, float* __restrict__ wT,
                            int O, int Dd) {
  int i = blockIdx.x * 256 + threadIdx.x;
  if (i < O * Dd) {
    int o = i / Dd, d = i - o * Dd;
    wT[d * O + o] = w[i];
  }
}

// ---------------- stage1a: xyz + y1 = x * w1^T ----------------
__global__ __launch_bounds__(256) void k_s1a(const float* __restrict__ x,
                                             const float* __restrict__ w1,
                                             float* __restrict__ xyz,
                                             float* __restrict__ y1) {
  __shared__ float w1s[192];
  int t = threadIdx.x;
  if (t < 192) w1s[t] = w1[t];
  int gid = blockIdx.x * 256 + t;  // 0 .. B*N-1
  int b = gid >> 13, n = gid & (NP - 1);
  __syncthreads();
  const size_t xb = (size_t)b * 3 * NP;
  float x0 = x[xb + n], x1 = x[xb + NP + n], x2 = x[xb + 2 * NP + n];
  xyz[(size_t)gid * 3 + 0] = x0;
  xyz[(size_t)gid * 3 + 1] = x1;
  xyz[(size_t)gid * 3 + 2] = x2;
  float* yo = y1 + (size_t)gid * 64;
#pragma unroll
  for (int o = 0; o < 64; o += 4) {
    float4 v;
    v.x = x0 * w1s[(o + 0) * 3] + x1 * w1s[(o + 0) * 3 + 1] + x2 * w1s[(o + 0) * 3 + 2];
    v.y = x0 * w1s[(o + 1) * 3] + x1 * w1s[(o + 1) * 3 + 1] + x2 * w1s[(o + 1) * 3 + 2];
    v.z = x0 * w1s[(o + 2) * 3] + x1 * w1s[(o + 2) * 3 + 1] + x2 * w1s[(o + 2) * 3 + 2];
    v.w = x0 * w1s[(o + 3) * 3] + x1 * w1s[(o + 3) * 3 + 1] + x2 * w1s[(o + 3) * 3 + 2];
    *(float4*)&yo[o] = v;
  }
}

// ---------------- per-channel (C=64) sum/sumsq over [M][64], float4 ----------------
__global__ __launch_bounds__(256) void k_colstats(const float* __restrict__ buf,
                                                  size_t ME4, float* __restrict__ part) {
  __shared__ float red[128];
  int t = threadIdx.x;
  if (t < 128) red[t] = 0.f;
  float s[4] = {0.f, 0.f, 0.f, 0.f}, q[4] = {0.f, 0.f, 0.f, 0.f};
  size_t stride = (size_t)gridDim.x * 256;
  size_t i0 = (size_t)blockIdx.x * 256 + t;
  int c0 = (int)((i0 * 4) & 63);
  for (size_t i = i0; i < ME4; i += stride) {
    float4 v = ((const float4*)buf)[i];
    s[0] += v.x; q[0] += v.x * v.x;
    s[1] += v.y; q[1] += v.y * v.y;
    s[2] += v.z; q[2] += v.z * v.z;
    s[3] += v.w; q[3] += v.w * v.w;
  }
  __syncthreads();
#pragma unroll
  for (int j = 0; j < 4; ++j) {
    atomicAdd(&red[c0 + j], s[j]);
    atomicAdd(&red[64 + c0 + j], q[j]);
  }
  __syncthreads();
  if (t < 128) atomicAdd(&part[(size_t)(blockIdx.x & 63) * 128 + t], red[t]);
}

// ---------------- BN finalize: partials[64][2*C] -> scale/shift[2*C] ----------------
__global__ void k_bnfinal(const float* __restrict__ part, const float* __restrict__ gamma,
                          const float* __restrict__ beta, float invcnt, int C,
                          float* __restrict__ sc) {
  int c = threadIdx.x;
  if (c >= C) return;
  float s = 0.f, q = 0.f;
  for (int p = 0; p < 64; ++p) {
    s += part[(size_t)p * 2 * C + c];
    q += part[(size_t)p * 2 * C + C + c];
  }
  float mean = s * invcnt;
  float var = fmaxf(q * invcnt - mean * mean, 0.f);
  float scale = gamma[c] * rsqrtf(var + 1e-5f);
  sc[c] = scale;
  sc[C + c] = beta[c] - mean * scale;
}

// ---------------- stage1c: y2 = w2 * relu(bn(y1)), 64-point tiles (in-place safe) ----
__global__ __launch_bounds__(256) void k_s1c(const float* __restrict__ y1,
                                             const float* __restrict__ w2T,
                                             const float* __restrict__ sc1,
                                             float* __restrict__ y2) {
  __shared__ __align__(16) float f1[64 * 65];
  __shared__ __align__(16) float w2s[64 * 64];
  __shared__ float scs[128];
  int t = threadIdx.x;
  if (t < 128) scs[t] = sc1[t];
  for (int i = t; i < 4096; i += 256) w2s[i] = w2T[i];
  size_t base = (size_t)blockIdx.x * 4096;
  __syncthreads();
  for (int i = t; i < 4096; i += 256) {
    int p = i >> 6, c = i & 63;
    float v = y1[base + i];
    v = fmaxf(0.f, v * scs[c] + scs[64 + c]);
    f1[p * 65 + c] = v;
  }
  __syncthreads();
  int pq = t & 15, oq = t >> 4;
  int p0 = pq * 4, o0 = oq * 4;
  float ac[4][4] = {};
  for (int c = 0; c < 64; ++c) {
    float4 wv = *(const float4*)&w2s[c * 64 + o0];
    float a0 = f1[(p0 + 0) * 65 + c];
    float a1 = f1[(p0 + 1) * 65 + c];
    float a2 = f1[(p0 + 2) * 65 + c];
    float a3 = f1[(p0 + 3) * 65 + c];
    ac[0][0] += a0 * wv.x; ac[0][1] += a0 * wv.y; ac[0][2] += a0 * wv.z; ac[0][3] += a0 * wv.w;
    ac[1][0] += a1 * wv.x; ac[1][1] += a1 * wv.y; ac[1][2] += a1 * wv.z; ac[1][3] += a1 * wv.w;
    ac[2][0] += a2 * wv.x; ac[2][1] += a2 * wv.y; ac[2][2] += a2 * wv.z; ac[2][3] += a2 * wv.w;
    ac[3][0] += a3 * wv.x; ac[3][1] += a3 * wv.y; ac[3][2] += a3 * wv.z; ac[3][3] += a3 * wv.w;
  }
#pragma unroll
  for (int i2 = 0; i2 < 4; ++i2) {
    float4 v = {ac[i2][0], ac[i2][1], ac[i2][2], ac[i2][3]};
    *(float4*)&y2[base + (size_t)(p0 + i2) * 64 + o0] = v;
  }
}

// ---------------- stage1e: in-place bn+relu over [M][64] ----------------
__global__ __launch_bounds__(256) void k_s1e(float* __restrict__ y2,
                                             const float* __restrict__ sc2, size_t ME4) {
  __shared__ float scs[128];
  int t = threadIdx.x;
  if (t < 128) scs[t] = sc2[t];
  __syncthreads();
  size_t stride = (size_t)gridDim.x * 256;
  for (size_t i = (size_t)blockIdx.x * 256 + t; i < ME4; i += stride) {
    float4 v = ((float4*)y2)[i];
    int c0 = (int)((i * 4) & 63);
    v.x = fmaxf(0.f, v.x * scs[c0 + 0] + scs[64 + c0 + 0]);
    v.y = fmaxf(0.f, v.y * scs[c0 + 1] + scs[64 + c0 + 1]);
    v.z = fmaxf(0.f, v.z * scs[c0 + 2] + scs[64 + c0 + 2]);
    v.w = fmaxf(0.f, v.w * scs[c0 + 3] + scs[64 + c0 + 3]);
    ((float4*)y2)[i] = v;
  }
}

// ---------------- FPS: one block per batch ----------------
template <int PPT>
__global__ void k_fps(const float* __restrict__ xyz, int N, int S,
                      int* __restrict__ fidx, float* __restrict__ sxyz) {
  const int T = blockDim.x;  // N / PPT
  const int t = threadIdx.x;
  const int b = blockIdx.x;
  const float* base = xyz + (size_t)b * N * 3;
  float cx[PPT], cy[PPT], cz[PPT], dist[PPT];
#pragma unroll
  for (int j = 0; j < PPT; ++j) {
    int n = t + j * T;
    cx[j] = base[(size_t)n * 3 + 0];
    cy[j] = base[(size_t)n * 3 + 1];
    cz[j] = base[(size_t)n * 3 + 2];
    dist[j] = 1e10f;
  }
  __shared__ float sx, sy, sz;
  __shared__ float wv[16];
  __shared__ int wi[16];
  if (t == 0) {
    fidx[(size_t)b * S] = 0;
    float gx = base[0], gy = base[1], gz = base[2];
    sx = gx; sy = gy; sz = gz;
    sxyz[((size_t)b * S) * 3 + 0] = gx;
    sxyz[((size_t)b * S) * 3 + 1] = gy;
    sxyz[((size_t)b * S) * 3 + 2] = gz;
  }
  __syncthreads();
  for (int it = 1; it < S; ++it) {
    float px = sx, py = sy, pz = sz;
    float bv = -1.0f;
    int bi = 0x7FFFFFFF;
#pragma unroll
    for (int j = 0; j < PPT; ++j) {
      float d = dist3(cx[j], cy[j], cz[j], px, py, pz);
      float dj = fminf(dist[j], d);
      dist[j] = dj;
      if (dj > bv) { bv = dj; bi = t + j * T; }  // j increasing -> first idx in thread
    }
#pragma unroll
    for (int off = 32; off > 0; off >>= 1) {
      float ov = __shfl_xor(bv, off);
      int oi = __shfl_xor(bi, off);
      if (ov > bv || (ov == bv && oi < bi)) { bv = ov; bi = oi; }
    }
    int wid = t >> 6;
    if ((t & 63) == 0) { wv[wid] = bv; wi[wid] = bi; }
    __syncthreads();
    if (t == 0) {
      int nw = T >> 6;
      float v = wv[0];
      int ii = wi[0];
      for (int w2_ = 1; w2_ < nw; ++w2_)
        if (wv[w2_] > v || (wv[w2_] == v && wi[w2_] < ii)) { v = wv[w2_]; ii = wi[w2_]; }
      fidx[(size_t)b * S + it] = ii;
      float gx = base[(size_t)ii * 3 + 0];
      float gy = base[(size_t)ii * 3 + 1];
      float gz = base[(size_t)ii * 3 + 2];
      sx = gx; sy = gy; sz = gz;
      sxyz[((size_t)b * S + it) * 3 + 0] = gx;
      sxyz[((size_t)b * S + it) * 3 + 1] = gy;
      sxyz[((size_t)b * S + it) * 3 + 2] = gz;
    }
    __syncthreads();
  }
}

// ---------------- KNN top-32 (iterative argmin) ----------------
template <int NMAX>
__global__ __launch_bounds__(256) void k_knn(const float* __restrict__ cxyz,
                                             const float* __restrict__ qxyz, int N, int S,
                                             int* __restrict__ knn) {
  __shared__ float dist[NMAX];
  __shared__ float wv[4];
  __shared__ int wi[4];
  const int t = threadIdx.x;
  const int bs = blockIdx.x;
  const int b = bs / S;
  float qx = qxyz[(size_t)bs * 3 + 0];
  float qy = qxyz[(size_t)bs * 3 + 1];
  float qz = qxyz[(size_t)bs * 3 + 2];
  float qq = sumsq3(qx, qy, qz);
  const float* cb = cxyz + (size_t)b * N * 3;
  for (int n = t; n < N; n += 256)
    dist[n] = knndist(qx, qy, qz, qq, cb[(size_t)n * 3], cb[(size_t)n * 3 + 1], cb[(size_t)n * 3 + 2]);
  __syncthreads();
  for (int r = 0; r < 32; ++r) {
    float bvv = 3.0e38f;
    int bii = 0x7FFFFFFF;
    for (int n = t; n < N; n += 256) {
      float d = dist[n];
      if (d < bvv) { bvv = d; bii = n; }
    }
#pragma unroll
    for (int off = 32; off > 0; off >>= 1) {
      float ov = __shfl_xor(bvv, off);
      int oi = __shfl_xor(bii, off);
      if (ov < bvv || (ov == bvv && oi < bii)) { bvv = ov; bii = oi; }
    }
    int wid = t >> 6;
    if ((t & 63) == 0) { wv[wid] = bvv; wi[wid] = bii; }
    __syncthreads();
    if (t == 0) {
      float v = wv[0];
      int ii = wi[0];
      for (int w2_ = 1; w2_ < 4; ++w2_)
        if (wv[w2_] < v || (wv[w2_] == v && wi[w2_] < ii)) { v = wv[w2_]; ii = wi[w2_]; }
      knn[(size_t)bs * 32 + r] = ii;
      dist[ii] = 3.0e38f;
    }
    __syncthreads();
  }
}

// ---------------- shared helpers for SG GEMMs ----------------
__device__ __forceinline__ int swzcol(int d, int k) {
  return (k & 3) | ((((unsigned(k) >> 2) ^ (unsigned(d) >> 2)) & 7) << 2);
}

// X: [D2][32] swizzled LDS; WT: [D2][O] global; wch: [CH][O] LDS staging.
template <int D2, int O, int NT, int CH>
__device__ __forceinline__ void sg_gemm(const float* __restrict__ X,
                                        const float* __restrict__ WT,
                                        float* __restrict__ wch, int t, int o0, int kq,
                                        float (&ac)[4][4]) {
  constexpr int K = 32;
#pragma unroll
  for (int i2 = 0; i2 < 4; ++i2)
#pragma unroll
    for (int j = 0; j < 4; ++j) ac[i2][j] = 0.f;
  for (int dc = 0; dc < D2; dc += CH) {
    __syncthreads();
    for (int i = t; i < CH * O; i += NT) wch[i] = WT[(size_t)dc * O + i];
    __syncthreads();
#pragma unroll 8
    for (int dd = 0; dd < CH; ++dd) {
      int d = dc + dd;
      const float4 wv = *(const float4*)&wch[dd * O + o0];
      const float4 av = *(const float4*)&X[d * K + ((kq ^ ((d >> 2) & 7)) << 2)];
      ac[0][0] += wv.x * av.x; ac[0][1] += wv.x * av.y; ac[0][2] += wv.x * av.z; ac[0][3] += wv.x * av.w;
      ac[1][0] += wv.y * av.x; ac[1][1] += wv.y * av.y; ac[1][2] += wv.y * av.z; ac[1][3] += wv.y * av.w;
      ac[2][0] += wv.z * av.x; ac[2][1] += wv.z * av.y; ac[2][2] += wv.z * av.z; ac[2][3] += wv.z * av.w;
      ac[3][0] += wv.w * av.x; ac[3][1] += wv.w * av.y; ac[3][2] += wv.w * av.z; ac[3][3] += wv.w * av.w;
    }
  }
}

// gather agg = [grouped-q | q] into swizzled LDS
template <int D, int NT>
__device__ __forceinline__ void sg_gather(const float* __restrict__ f, int Nf, int b,
                                          const int* __restrict__ nidx,
                                          const float* __restrict__ fq,
                                          float* __restrict__ agg, int t) {
  constexpr int K = 32;
  for (int idx = t; idx < K * D; idx += NT) {
    int k = idx / D, dd = idx - k * D;
    float v = f[((size_t)b * Nf + nidx[k]) * D + dd];
    float q = fq[dd];
    agg[dd * K + swzcol(dd, k)] = v - q;
    agg[(D + dd) * K + swzcol(D + dd, k)] = q;
  }
}

// ---------------- pass A: gather + GEMM A -> statsA only ----------------
template <int D, int NT>
__global__ __launch_bounds__(NT) void k_sgA(const float* __restrict__ f, int Nf, int S,
                                            const int* __restrict__ fpsidx,
                                            const int* __restrict__ knn,
                                            const float* __restrict__ waT,
                                            float* __restrict__ statsOut) {
  constexpr int D2 = 2 * D, O = D2, K = 32, CH = 16;
  __shared__ __align__(16) float agg[D2 * K];
  __shared__ __align__(16) float wch[CH * O];
  __shared__ float fq[D];
  __shared__ int nidx[K];
  __shared__ float red[2 * O];
  const int t = threadIdx.x;
  const int bs = blockIdx.x;
  const int b = bs / S;
  const int qi = fpsidx[bs];
  if (t < K) nidx[t] = knn[(size_t)bs * K + t];
  for (int i = t; i < D; i += NT) fq[i] = f[((size_t)b * Nf + qi) * D + i];
  __syncthreads();
  sg_gather<D, NT>(f, Nf, b, nidx, fq, agg, t);
  const int oq = t >> 3, kq = t & 7;
  const int o0 = oq * 4;
  float acc[4][4];
  sg_gemm<D2, O, NT, CH>(agg, waT, wch, t, o0, kq, acc);  // 1st barrier covers gather
  // stats via 8-lane shuffle groups (kq within one wave)
#pragma unroll
  for (int i2 = 0; i2 < 4; ++i2) {
    float sv = acc[i2][0] + acc[i2][1] + acc[i2][2] + acc[i2][3];
    float sq = acc[i2][0] * acc[i2][0] + acc[i2][1] * acc[i2][1] +
               acc[i2][2] * acc[i2][2] + acc[i2][3] * acc[i2][3];
#pragma unroll
    for (int m = 1; m < 8; m <<= 1) {
      sv += __shfl_xor(sv, m);
      sq += __shfl_xor(sq, m);
    }
    if (kq == 0) {
      red[o0 + i2] = sv;
      red[O + o0 + i2] = sq;
    }
  }
  __syncthreads();
  float* slot = statsOut + (size_t)(bs & 63) * (2 * O);
  for (int i = t; i < 2 * O; i += NT) atomicAdd(&slot[i], red[i]);
}

// ------- pass AB: recompute A, bnA+relu, GEMM B -> statsB + per-(bs,o) max/min yB ---
template <int D, int NT>
__global__ __launch_bounds__(NT) void k_sgAB(const float* __restrict__ f, int Nf, int S,
                                             const int* __restrict__ fpsidx,
                                             const int* __restrict__ knn,
                                             const float* __restrict__ waT,
                                             const float* __restrict__ wbT,
                                             const float* __restrict__ bnA,
                                             float* __restrict__ statsOut,
                                             float* __restrict__ mm) {
  constexpr int D2 = 2 * D, O = D2, K = 32, CH = 16;
  __shared__ __align__(16) float agg[D2 * K];  // reused as zA after GEMM A
  __shared__ __align__(16) float wch[CH * O];
  __shared__ float fq[D];
  __shared__ int nidx[K];
  __shared__ float red[2 * O];
  __shared__ float scb[2 * O];
  const int t = threadIdx.x;
  const int bs = blockIdx.x;
  const int b = bs / S;
  const int qi = fpsidx[bs];
  if (t < K) nidx[t] = knn[(size_t)bs * K + t];
  for (int i = t; i < D; i += NT) fq[i] = f[((size_t)b * Nf + qi) * D + i];
  for (int i = t; i < 2 * O; i += NT) scb[i] = bnA[i];
  __syncthreads();
  sg_gather<D, NT>(f, Nf, b, nidx, fq, agg, t);
  const int oq = t >> 3, kq = t & 7;
  const int o0 = oq * 4, k0 = kq * 4;
  float acc[4][4];
  sg_gemm<D2, O, NT, CH>(agg, waT, wch, t, o0, kq, acc);
  __syncthreads();  // all reads of agg complete before overwrite
#pragma unroll
  for (int i2 = 0; i2 < 4; ++i2) {
    float sA = scb[o0 + i2], tA = scb[O + o0 + i2];
#pragma unroll
    for (int j = 0; j < 4; ++j) {
      float z = fmaxf(0.f, acc[i2][j] * sA + tA);
      agg[(o0 + i2) * K + swzcol(o0 + i2, k0 + j)] = z;  // zA in-place
    }
  }
  float acc2[4][4];
  sg_gemm<D2, O, NT, CH>(agg, wbT, wch, t, o0, kq, acc2);  // 1st barrier covers zA
  // stats + max/min via 8-lane shuffle groups
  float* mrow = mm + (size_t)bs * 2 * O;
#pragma unroll
  for (int i2 = 0; i2 < 4; ++i2) {
    float sv = acc2[i2][0] + acc2[i2][1] + acc2[i2][2] + acc2[i2][3];
    float sq = acc2[i2][0] * acc2[i2][0] + acc2[i2][1] * acc2[i2][1] +
               acc2[i2][2] * acc2[i2][2] + acc2[i2][3] * acc2[i2][3];
    float mx = fmaxf(fmaxf(acc2[i2][0], acc2[i2][1]), fmaxf(acc2[i2][2], acc2[i2][3]));
    float mn = fminf(fminf(acc2[i2][0], acc2[i2][1]), fminf(acc2[i2][2], acc2[i2][3]));
#pragma unroll
    for (int m = 1; m < 8; m <<= 1) {
      sv += __shfl_xor(sv, m);
      sq += __shfl_xor(sq, m);
      mx = fmaxf(mx, __shfl_xor(mx, m));
      mn = fminf(mn, __shfl_xor(mn, m));
    }
    if (kq == 0) {
      red[o0 + i2] = sv;
      red[O + o0 + i2] = sq;
      mrow[o0 + i2] = mx;
      mrow[O + o0 + i2] = mn;
    }
  }
  __syncthreads();
  float* slot = statsOut + (size_t)(bs & 63) * (2 * O);
  for (int i = t; i < 2 * O; i += NT) atomicAdd(&slot[i], red[i]);
}

// ------- finalize: out = relu(sB * (sB>=0 ? maxYB : minYB) + tB) ------------------
template <int O>
__global__ __launch_bounds__(256) void k_fin(const float* __restrict__ mm,
                                             const float* __restrict__ bnB, int S,
                                             float* __restrict__ out, int finalOut) {
  int idx = blockIdx.x * 256 + threadIdx.x;
  int o, bs;
  if (finalOut) {
    int s = idx % S;
    int bo = idx / S;
    o = bo % O;
    int b = bo / O;
    bs = b * S + s;
  } else {
    o = idx % O;
    bs = idx / O;
  }
  float sB = bnB[o], tB = bnB[O + o];
  const float* r = mm + (size_t)bs * 2 * O;
  float ext = (sB >= 0.f) ? r[o] : r[O + o];
  out[idx] = fmaxf(0.f, sB * ext + tB);
}

// ---------------- fallback 3-pass SG kernel (recompute; used if ws too small) ------
template <int D, int PASS, int NT>
__global__ __launch_bounds__(NT) void k_sg(const float* __restrict__ f, int Nf, int S,
                                           const int* __restrict__ fpsidx,
                                           const int* __restrict__ knn,
                                           const float* __restrict__ waT,
                                           const float* __restrict__ wbT,
                                           const float* __restrict__ bnA,
                                           const float* __restrict__ bnB,
                                           float* __restrict__ statsOut,
                                           float* __restrict__ out, int finalOut) {
  constexpr int D2 = 2 * D, O = D2, K = 32;
  __shared__ __align__(16) float agg[D2 * K];
  __shared__ __align__(16) float wch[32 * O];
  __shared__ float fq[D];
  __shared__ int nidx[K];
  __shared__ __align__(16) float zA[(PASS >= 1) ? D2 * K : 1];
  __shared__ float red[2 * O];
  const int t = threadIdx.x;
  const int bs = blockIdx.x;
  const int b = bs / S, s = bs - b * S;
  const int qi = fpsidx[bs];
  if (t < K) nidx[t] = knn[(size_t)bs * K + t];
  for (int i = t; i < D; i += NT) fq[i] = f[((size_t)b * Nf + qi) * D + i];
  __syncthreads();
  sg_gather<D, NT>(f, Nf, b, nidx, fq, agg, t);
  const int oq = t >> 3, kq = t & 7;
  const int o0 = oq * 4, k0 = kq * 4;
  float acc[4][4];
  sg_gemm<D2, O, NT, 32>(agg, waT, wch, t, o0, kq, acc);

  if constexpr (PASS == 0) {
    for (int i = t; i < 2 * O; i += NT) red[i] = 0.f;
    __syncthreads();
#pragma unroll
    for (int i2 = 0; i2 < 4; ++i2) {
      float sv = 0.f, sq = 0.f;
#pragma unroll
      for (int j = 0; j < 4; ++j) {
        float v = acc[i2][j];
        sv += v;
        sq += v * v;
      }
      atomicAdd(&red[o0 + i2], sv);
      atomicAdd(&red[O + o0 + i2], sq);
    }
    __syncthreads();
    float* slot = statsOut + (size_t)(bs & 63) * (2 * O);
    for (int i = t; i < 2 * O; i += NT) atomicAdd(&slot[i], red[i]);
    return;
  } else {
#pragma unroll
    for (int i2 = 0; i2 < 4; ++i2) {
      float sA = bnA[o0 + i2], tA = bnA[O + o0 + i2];
#pragma unroll
      for (int j = 0; j < 4; ++j) {
        float z = fmaxf(0.f, acc[i2][j] * sA + tA);
        zA[(o0 + i2) * K + swzcol(o0 + i2, k0 + j)] = z;
      }
    }
    float acc2[4][4];
    sg_gemm<D2, O, NT, 32>(zA, wbT, wch, t, o0, kq, acc2);

    if constexpr (PASS == 1) {
      for (int i = t; i < 2 * O; i += NT) red[i] = 0.f;
      __syncthreads();
#pragma unroll
      for (int i2 = 0; i2 < 4; ++i2) {
        float sv = 0.f, sq = 0.f;
#pragma unroll
        for (int j = 0; j < 4; ++j) {
          float v = acc2[i2][j];
          sv += v;
          sq += v * v;
        }
        atomicAdd(&red[o0 + i2], sv);
        atomicAdd(&red[O + o0 + i2], sq);
      }
      __syncthreads();
      float* slot = statsOut + (size_t)(bs & 63) * (2 * O);
      for (int i = t; i < 2 * O; i += NT) atomicAdd(&slot[i], red[i]);
      return;
    } else {
      for (int i = t; i < O; i += NT) red[i] = 0.f;
      __syncthreads();
#pragma unroll
      for (int i2 = 0; i2 < 4; ++i2) {
        float sB = bnB[o0 + i2], tB = bnB[O + o0 + i2];
        float m = 0.f;
#pragma unroll
        for (int j = 0; j < 4; ++j) m = fmaxf(m, fmaxf(0.f, acc2[i2][j] * sB + tB));
        atomicMax((int*)&red[o0 + i2], __float_as_int(m));  // relu output >= 0
      }
      __syncthreads();
      if (finalOut) {
        for (int i = t; i < O; i += NT) out[((size_t)b * O + i) * S + s] = red[i];
      } else {
        for (int i = t; i < O; i += NT) out[(size_t)bs * O + i] = red[i];
      }
    }
  }
}

// ---------------- host launch ----------------
extern "C" void kernel_launch(void* const* d_in, const int* in_sizes, int n_in,
                              void* d_out, int out_size, void* d_ws, size_t ws_size,
                              hipStream_t stream) {
  (void)in_sizes; (void)n_in; (void)out_size;
  const float* x    = (const float*)d_in[0];
  const float* w1   = (const float*)d_in[1];
  const float* g1   = (const float*)d_in[2];
  const float* b1   = (const float*)d_in[3];
  const float* w2   = (const float*)d_in[4];
  const float* g2   = (const float*)d_in[5];
  const float* b2   = (const float*)d_in[6];
  const float* s1wa = (const float*)d_in[7];
  const float* s1ga = (const float*)d_in[8];
  const float* s1ba = (const float*)d_in[9];
  const float* s1wb = (const float*)d_in[10];
  const float* s1gb = (const float*)d_in[11];
  const float* s1bb = (const float*)d_in[12];
  const float* s2wa = (const float*)d_in[13];
  const float* s2ga = (const float*)d_in[14];
  const float* s2ba = (const float*)d_in[15];
  const float* s2wb = (const float*)d_in[16];
  const float* s2gb = (const float*)d_in[17];
  const float* s2bb = (const float*)d_in[18];
  float* out = (float*)d_out;

  char* wsp = (char*)d_ws;
  size_t off = 0;
  auto alloc = [&](size_t floats) {
    void* p = wsp + off;
    off += ((floats * 4 + 255) & ~(size_t)255);
    return p;
  };
  float* xyz  = (float*)alloc(786432);     // [B][N][3]
  float* y1   = (float*)alloc(16777216);   // [B*N][64] conv1 raw -> conv2 in-place -> features
  float* y2f  = y1;                        // alias (k_s1c tile-in-LDS then overwrite: safe)
  float* f1f  = (float*)alloc(2097152);    // [B][S1][128]
  float* xyz1 = (float*)alloc(49152);      // [B][S1][3]
  float* xyz2 = (float*)alloc(24576);      // [B][S2][3]
  int* fi1    = (int*)alloc(16384);        // [B][S1]
  int* fi2    = (int*)alloc(8192);         // [B][S2]
  int* kn1    = (int*)alloc(524288);       // [B][S1][32]
  int* kn2    = (int*)alloc(262144);       // [B][S2][32]
  float* w2T  = (float*)alloc(4096);
  float* waT1 = (float*)alloc(16384);
  float* wbT1 = (float*)alloc(16384);
  float* waT2 = (float*)alloc(65536);
  float* wbT2 = (float*)alloc(65536);
  float* stats = (float*)alloc(116480);
  float* part_s1 = stats;                  // [64][128]
  float* part_s2 = stats + 8192;
  float* partA1  = stats + 16384;          // [64][256]
  float* partB1  = stats + 32768;
  float* partA2  = stats + 49152;          // [64][512]
  float* partB2  = stats + 81920;
  float* sc1  = stats + 114688;            // [2*64]
  float* sc2  = sc1 + 128;
  float* bnA1 = sc2 + 128;                 // [2*128]
  float* bnB1 = bnA1 + 256;
  float* bnA2 = bnB1 + 256;                // [2*256]
  float* bnB2 = bnA2 + 512;
  // per-(bs,o) max/min of yB: max(16384*256, 8192*512) = 4,194,304 floats (16 MB)
  float* mm = (float*)alloc(4194304);
  const bool useNew = (off <= ws_size);    // constant per-harness -> graph-capture safe

  hipMemsetAsync(stats, 0, (size_t)114688 * 4, stream);

  // weight transposes
  k_transpose<<<(64 * 64 + 255) / 256, 256, 0, stream>>>(w2, w2T, 64, 64);
  k_transpose<<<(128 * 128 + 255) / 256, 256, 0, stream>>>(s1wa, waT1, 128, 128);
  k_transpose<<<(128 * 128 + 255) / 256, 256, 0, stream>>>(s1wb, wbT1, 128, 128);
  k_transpose<<<(256 * 256 + 255) / 256, 256, 0, stream>>>(s2wa, waT2, 256, 256);
  k_transpose<<<(256 * 256 + 255) / 256, 256, 0, stream>>>(s2wb, wbT2, 256, 256);

  const size_t MN = (size_t)NB * NP;  // 262144
  // stage 1
  k_s1a<<<(int)(MN / 256), 256, 0, stream>>>(x, w1, xyz, y1);
  k_colstats<<<1024, 256, 0, stream>>>(y1, MN * 16, part_s1);
  k_bnfinal<<<1, 64, 0, stream>>>(part_s1, g1, b1, 1.f / (float)MN, 64, sc1);
  k_s1c<<<(int)(MN / 64), 256, 0, stream>>>(y1, w2T, sc1, y2f);
  k_colstats<<<1024, 256, 0, stream>>>(y2f, MN * 16, part_s2);
  k_bnfinal<<<1, 64, 0, stream>>>(part_s2, g2, b2, 1.f / (float)MN, 64, sc2);
  k_s1e<<<2048, 256, 0, stream>>>(y2f, sc2, MN * 16);

  // sampling/grouping indices
  k_fps<8><<<NB, 1024, 0, stream>>>(xyz, NP, 512, fi1, xyz1);
  k_knn<8192><<<NB * 512, 256, 0, stream>>>(xyz, xyz1, NP, 512, kn1);

  const float icA1 = 1.f / (32.f * 512.f * 32.f);
  const float icA2 = 1.f / (32.f * 256.f * 32.f);

  if (useNew) {
    // ---- SG block 1: A(stats) -> AB(stats+minmax) -> finalize ----
    k_sgA<64, 256><<<NB * 512, 256, 0, stream>>>(y2f, NP, 512, fi1, kn1, waT1, partA1);
    k_bnfinal<<<1, 128, 0, stream>>>(partA1, s1ga, s1ba, icA1, 128, bnA1);
    k_sgAB<64, 256><<<NB * 512, 256, 0, stream>>>(y2f, NP, 512, fi1, kn1, waT1, wbT1,
                                                  bnA1, partB1, mm);
    k_bnfinal<<<1, 128, 0, stream>>>(partB1, s1gb, s1bb, icA1, 128, bnB1);
    k_fin<128><<<8192, 256, 0, stream>>>(mm, bnB1, 512, f1f, 0);

    k_fps<2><<<NB, 256, 0, stream>>>(xyz1, 512, 256, fi2, xyz2);
    k_knn<512><<<NB * 256, 256, 0, stream>>>(xyz1, xyz2, 512, 256, kn2);

    // ---- SG block 2 ----
    k_sgA<128, 512><<<NB * 256, 512, 0, stream>>>(f1f, 512, 256, fi2, kn2, waT2, partA2);
    k_bnfinal<<<1, 256, 0, stream>>>(partA2, s2ga, s2ba, icA2, 256, bnA2);
    k_sgAB<128, 512><<<NB * 256, 512, 0, stream>>>(f1f, 512, 256, fi2, kn2, waT2, wbT2,
                                                   bnA2, partB2, mm);
    k_bnfinal<<<1, 256, 0, stream>>>(partB2, s2gb, s2bb, icA2, 256, bnB2);
    k_fin<256><<<8192, 256, 0, stream>>>(mm, bnB2, 256, out, 1);
  } else {
    // ---- fallback: original 3-pass recompute ----
    k_sg<64, 0, 256><<<NB * 512, 256, 0, stream>>>(y2f, NP, 512, fi1, kn1, waT1, wbT1,
                                                   nullptr, nullptr, partA1, nullptr, 0);
    k_bnfinal<<<1, 128, 0, stream>>>(partA1, s1ga, s1ba, icA1, 128, bnA1);
    k_sg<64, 1, 256><<<NB * 512, 256, 0, stream>>>(y2f, NP, 512, fi1, kn1, waT1, wbT1,
                                                   bnA1, nullptr, partB1, nullptr, 0);
    k_bnfinal<<<1, 128, 0, stream>>>(partB1, s1gb, s1bb, icA1, 128, bnB1);
    k_sg<64, 2, 256><<<NB * 512, 256, 0, stream>>>(y2f, NP, 512, fi1, kn1, waT1, wbT1,
                                                   bnA1, bnB1, nullptr, f1f, 0);

    k_fps<2><<<NB, 256, 0, stream>>>(xyz1, 512, 256, fi2, xyz2);
    k_knn<512><<<NB * 256, 256, 0, stream>>>(xyz1, xyz2, 512, 256, kn2);

    k_sg<128, 0, 512><<<NB * 256, 512, 0, stream>>>(f1f, 512, 256, fi2, kn2, waT2, wbT2,
                                                    nullptr, nullptr, partA2, nullptr, 0);
    k_bnfinal<<<1, 256, 0, stream>>>(partA2, s2ga, s2ba, icA2, 256, bnA2);
    k_sg<128, 1, 512><<<NB * 256, 512, 0, stream>>>(f1f, 512, 256, fi2, kn2, waT2, wbT2,
                                                    bnA2, nullptr, partB2, nullptr, 0);
    k_bnfinal<<<1, 256, 0, stream>>>(partB2, s2gb, s2bb, icA2, 256, bnB2);
    k_sg<128, 2, 512><<<NB * 256, 512, 0, stream>>>(f1f, 512, 256, fi2, kn2, waT2, wbT2,
                                                    bnA2, bnB2, nullptr, out, 1);
  }
}

// Round 8
// 4345.007 us; speedup vs baseline: 2.1714x; 1.3800x over previous
//
#include <hip/hip_runtime.h>
#include <hip/hip_bf16.h>

// ---------------- constants ----------------
// B=32, N=8192, S1=512, S2=256, K=32
#define NB 32
#define NP 8192

// ---------- distance helpers (match numpy: no FMA contraction) ----------
__device__ __forceinline__ float dist3(float ax, float ay, float az,
                                       float bx, float by, float bz) {
#pragma clang fp contract(off)
  float dx = ax - bx, dy = ay - by, dz = az - bz;
  return dx * dx + dy * dy + dz * dz;
}
__device__ __forceinline__ float sumsq3(float x, float y, float z) {
#pragma clang fp contract(off)
  return x * x + y * y + z * z;
}
__device__ __forceinline__ float knndist(float qx, float qy, float qz, float qq,
                                         float cx, float cy, float cz) {
#pragma clang fp contract(off)
  float dot = qx * cx + qy * cy + qz * cz;
  float cc = cx * cx + cy * cy + cz * cz;
  return (qq - 2.0f * dot) + cc;
}

// ---------------- weight transpose: wT[d][O] = w[o][d] ----------------
__global__ void k_transpose(const float* __restrict__ w, float* __restrict__ wT,
                            int O, int Dd) {
  int i = blockIdx.x * 256 + threadIdx.x;
  if (i < O * Dd) {
    int o = i / Dd, d = i - o * Dd;
    wT[d * O + o] = w[i];
  }
}

// ---------------- WdT[d][o] = w[o][D+d] - w[o][d]  (d < D, split correction) -------
__global__ void k_wdiff(const float* __restrict__ w, float* __restrict__ WdT,
                        int O, int D) {
  int i = blockIdx.x * 256 + threadIdx.x;
  if (i < D * O) {
    int d = i / O, o = i - d * O;
    WdT[i] = w[o * 2 * D + D + d] - w[o * 2 * D + d];
  }
}

// ---------------- stage1a: xyz + y1 = x * w1^T ----------------
__global__ __launch_bounds__(256) void k_s1a(const float* __restrict__ x,
                                             const float* __restrict__ w1,
                                             float* __restrict__ xyz,
                                             float* __restrict__ y1) {
  __shared__ float w1s[192];
  int t = threadIdx.x;
  if (t < 192) w1s[t] = w1[t];
  int gid = blockIdx.x * 256 + t;  // 0 .. B*N-1
  int b = gid >> 13, n = gid & (NP - 1);
  __syncthreads();
  const size_t xb = (size_t)b * 3 * NP;
  float x0 = x[xb + n], x1 = x[xb + NP + n], x2 = x[xb + 2 * NP + n];
  xyz[(size_t)gid * 3 + 0] = x0;
  xyz[(size_t)gid * 3 + 1] = x1;
  xyz[(size_t)gid * 3 + 2] = x2;
  float* yo = y1 + (size_t)gid * 64;
#pragma unroll
  for (int o = 0; o < 64; o += 4) {
    float4 v;
    v.x = x0 * w1s[(o + 0) * 3] + x1 * w1s[(o + 0) * 3 + 1] + x2 * w1s[(o + 0) * 3 + 2];
    v.y = x0 * w1s[(o + 1) * 3] + x1 * w1s[(o + 1) * 3 + 1] + x2 * w1s[(o + 1) * 3 + 2];
    v.z = x0 * w1s[(o + 2) * 3] + x1 * w1s[(o + 2) * 3 + 1] + x2 * w1s[(o + 2) * 3 + 2];
    v.w = x0 * w1s[(o + 3) * 3] + x1 * w1s[(o + 3) * 3 + 1] + x2 * w1s[(o + 3) * 3 + 2];
    *(float4*)&yo[o] = v;
  }
}

// ---------------- per-channel (C=64) sum/sumsq over [M][64], float4 ----------------
__global__ __launch_bounds__(256) void k_colstats(const float* __restrict__ buf,
                                                  size_t ME4, float* __restrict__ part) {
  __shared__ float red[128];
  int t = threadIdx.x;
  if (t < 128) red[t] = 0.f;
  float s[4] = {0.f, 0.f, 0.f, 0.f}, q[4] = {0.f, 0.f, 0.f, 0.f};
  size_t stride = (size_t)gridDim.x * 256;
  size_t i0 = (size_t)blockIdx.x * 256 + t;
  int c0 = (int)((i0 * 4) & 63);
  for (size_t i = i0; i < ME4; i += stride) {
    float4 v = ((const float4*)buf)[i];
    s[0] += v.x; q[0] += v.x * v.x;
    s[1] += v.y; q[1] += v.y * v.y;
    s[2] += v.z; q[2] += v.z * v.z;
    s[3] += v.w; q[3] += v.w * v.w;
  }
  __syncthreads();
#pragma unroll
  for (int j = 0; j < 4; ++j) {
    atomicAdd(&red[c0 + j], s[j]);
    atomicAdd(&red[64 + c0 + j], q[j]);
  }
  __syncthreads();
  if (t < 128) atomicAdd(&part[(size_t)(blockIdx.x & 63) * 128 + t], red[t]);
}

// ---------------- BN finalize: partials[64][2*C] -> scale/shift[2*C] ----------------
__global__ void k_bnfinal(const float* __restrict__ part, const float* __restrict__ gamma,
                          const float* __restrict__ beta, float invcnt, int C,
                          float* __restrict__ sc) {
  int c = threadIdx.x;
  if (c >= C) return;
  float s = 0.f, q = 0.f;
  for (int p = 0; p < 64; ++p) {
    s += part[(size_t)p * 2 * C + c];
    q += part[(size_t)p * 2 * C + C + c];
  }
  float mean = s * invcnt;
  float var = fmaxf(q * invcnt - mean * mean, 0.f);
  float scale = gamma[c] * rsqrtf(var + 1e-5f);
  sc[c] = scale;
  sc[C + c] = beta[c] - mean * scale;
}

// ---------------- stage1c: y2 = w2 * relu(bn(y1)), 64-point tiles (in-place safe) ----
__global__ __launch_bounds__(256) void k_s1c(const float* __restrict__ y1,
                                             const float* __restrict__ w2T,
                                             const float* __restrict__ sc1,
                                             float* __restrict__ y2) {
  __shared__ __align__(16) float f1[64 * 65];
  __shared__ __align__(16) float w2s[64 * 64];
  __shared__ float scs[128];
  int t = threadIdx.x;
  if (t < 128) scs[t] = sc1[t];
  for (int i = t; i < 4096; i += 256) w2s[i] = w2T[i];
  size_t base = (size_t)blockIdx.x * 4096;
  __syncthreads();
  for (int i = t; i < 4096; i += 256) {
    int p = i >> 6, c = i & 63;
    float v = y1[base + i];
    v = fmaxf(0.f, v * scs[c] + scs[64 + c]);
    f1[p * 65 + c] = v;
  }
  __syncthreads();
  int pq = t & 15, oq = t >> 4;
  int p0 = pq * 4, o0 = oq * 4;
  float ac[4][4] = {};
  for (int c = 0; c < 64; ++c) {
    float4 wv = *(const float4*)&w2s[c * 64 + o0];
    float a0 = f1[(p0 + 0) * 65 + c];
    float a1 = f1[(p0 + 1) * 65 + c];
    float a2 = f1[(p0 + 2) * 65 + c];
    float a3 = f1[(p0 + 3) * 65 + c];
    ac[0][0] += a0 * wv.x; ac[0][1] += a0 * wv.y; ac[0][2] += a0 * wv.z; ac[0][3] += a0 * wv.w;
    ac[1][0] += a1 * wv.x; ac[1][1] += a1 * wv.y; ac[1][2] += a1 * wv.z; ac[1][3] += a1 * wv.w;
    ac[2][0] += a2 * wv.x; ac[2][1] += a2 * wv.y; ac[2][2] += a2 * wv.z; ac[2][3] += a2 * wv.w;
    ac[3][0] += a3 * wv.x; ac[3][1] += a3 * wv.y; ac[3][2] += a3 * wv.z; ac[3][3] += a3 * wv.w;
  }
#pragma unroll
  for (int i2 = 0; i2 < 4; ++i2) {
    float4 v = {ac[i2][0], ac[i2][1], ac[i2][2], ac[i2][3]};
    *(float4*)&y2[base + (size_t)(p0 + i2) * 64 + o0] = v;
  }
}

// ---------------- stage1e: in-place bn+relu over [M][64] ----------------
__global__ __launch_bounds__(256) void k_s1e(float* __restrict__ y2,
                                             const float* __restrict__ sc2, size_t ME4) {
  __shared__ float scs[128];
  int t = threadIdx.x;
  if (t < 128) scs[t] = sc2[t];
  __syncthreads();
  size_t stride = (size_t)gridDim.x * 256;
  for (size_t i = (size_t)blockIdx.x * 256 + t; i < ME4; i += stride) {
    float4 v = ((float4*)y2)[i];
    int c0 = (int)((i * 4) & 63);
    v.x = fmaxf(0.f, v.x * scs[c0 + 0] + scs[64 + c0 + 0]);
    v.y = fmaxf(0.f, v.y * scs[c0 + 1] + scs[64 + c0 + 1]);
    v.z = fmaxf(0.f, v.z * scs[c0 + 2] + scs[64 + c0 + 2]);
    v.w = fmaxf(0.f, v.w * scs[c0 + 3] + scs[64 + c0 + 3]);
    ((float4*)y2)[i] = v;
  }
}

// ---------------- FPS: LDS-resident coords, 1 barrier/iter ----------------
template <int N, int S, int PPT>
__global__ __launch_bounds__(N / PPT) void k_fps(const float* __restrict__ xyz,
                                                 int* __restrict__ fidx,
                                                 float* __restrict__ sxyz) {
  constexpr int T = N / PPT;
  constexpr int NW = T / 64;
  __shared__ float cl[N * 3];
  __shared__ float wv[2][NW];
  __shared__ int wi[2][NW];
  const int t = threadIdx.x;
  const int b = blockIdx.x;
  const float* base = xyz + (size_t)b * N * 3;
  for (int i = t; i < 3 * N; i += T) cl[i] = base[i];
  __syncthreads();
  float cx[PPT], cy[PPT], cz[PPT], dist[PPT];
#pragma unroll
  for (int j = 0; j < PPT; ++j) {
    int n = t + j * T;
    cx[j] = cl[n * 3 + 0];
    cy[j] = cl[n * 3 + 1];
    cz[j] = cl[n * 3 + 2];
    dist[j] = 1e10f;
  }
  float px = cl[0], py = cl[1], pz = cl[2];
  if (t == 0) {
    fidx[(size_t)b * S] = 0;
    sxyz[(size_t)b * S * 3 + 0] = px;
    sxyz[(size_t)b * S * 3 + 1] = py;
    sxyz[(size_t)b * S * 3 + 2] = pz;
  }
  int par = 0;
  for (int it = 1; it < S; ++it) {
    float bv = -1.0f;
    int bi = 0x7FFFFFFF;
#pragma unroll
    for (int j = 0; j < PPT; ++j) {
      float d = dist3(cx[j], cy[j], cz[j], px, py, pz);
      float dj = fminf(dist[j], d);
      dist[j] = dj;
      if (dj > bv) { bv = dj; bi = t + j * T; }  // j asc -> first (smallest n) in thread
    }
#pragma unroll
    for (int off = 32; off > 0; off >>= 1) {
      float ov = __shfl_xor(bv, off);
      int oi = __shfl_xor(bi, off);
      if (ov > bv || (ov == bv && oi < bi)) { bv = ov; bi = oi; }
    }
    if ((t & 63) == 0) { wv[par][t >> 6] = bv; wi[par][t >> 6] = bi; }
    __syncthreads();
    float v = wv[par][0];
    int ii = wi[par][0];
#pragma unroll
    for (int w = 1; w < NW; ++w) {
      float ov = wv[par][w];
      int oi = wi[par][w];
      if (ov > v || (ov == v && oi < ii)) { v = ov; ii = oi; }
    }
    px = cl[ii * 3 + 0]; py = cl[ii * 3 + 1]; pz = cl[ii * 3 + 2];
    if (t == 0) {
      fidx[(size_t)b * S + it] = ii;
      sxyz[((size_t)b * S + it) * 3 + 0] = px;
      sxyz[((size_t)b * S + it) * 3 + 1] = py;
      sxyz[((size_t)b * S + it) * 3 + 2] = pz;
    }
    par ^= 1;
  }
}

// ---------------- KNN top-32: register candidates + incremental local min ----------
template <int NPT>
__global__ __launch_bounds__(256) void k_knn(const float* __restrict__ cxyz,
                                             const float* __restrict__ qxyz, int S,
                                             int* __restrict__ knn) {
  constexpr int N = NPT * 256;
  __shared__ float wv[2][4];
  __shared__ int wi[2][4];
  const int t = threadIdx.x;
  const int bs = blockIdx.x;
  const int b = bs / S;
  float qx = qxyz[(size_t)bs * 3 + 0];
  float qy = qxyz[(size_t)bs * 3 + 1];
  float qz = qxyz[(size_t)bs * 3 + 2];
  float qq = sumsq3(qx, qy, qz);
  const float* cb = cxyz + (size_t)b * N * 3;
  float ds[NPT];
  float lmin = 3.0e38f;
  int li = 0x7FFFFFFF;
#pragma unroll
  for (int j = 0; j < NPT; ++j) {
    int n = t + j * 256;
    float d = knndist(qx, qy, qz, qq, cb[(size_t)n * 3], cb[(size_t)n * 3 + 1],
                      cb[(size_t)n * 3 + 2]);
    ds[j] = d;
    if (d < lmin) { lmin = d; li = n; }
  }
  int par = 0;
  for (int r = 0; r < 32; ++r) {
    float bv = lmin;
    int bi = li;
#pragma unroll
    for (int off = 32; off > 0; off >>= 1) {
      float ov = __shfl_xor(bv, off);
      int oi = __shfl_xor(bi, off);
      if (ov < bv || (ov == bv && oi < bi)) { bv = ov; bi = oi; }
    }
    if ((t & 63) == 0) { wv[par][t >> 6] = bv; wi[par][t >> 6] = bi; }
    __syncthreads();
    float v = wv[par][0];
    int ii = wi[par][0];
#pragma unroll
    for (int w = 1; w < 4; ++w) {
      float ov = wv[par][w];
      int oi = wi[par][w];
      if (ov < v || (ov == v && oi < ii)) { v = ov; ii = oi; }
    }
    if (t == 0) knn[(size_t)bs * 32 + r] = ii;
    if (li == ii) {  // only the owner rescans
#pragma unroll
      for (int j = 0; j < NPT; ++j)
        if (t + j * 256 == ii) ds[j] = 3.0e38f;
      lmin = 3.0e38f;
      li = 0x7FFFFFFF;
#pragma unroll
      for (int j = 0; j < NPT; ++j)
        if (ds[j] < lmin) { lmin = ds[j]; li = t + j * 256; }
    }
    par ^= 1;
  }
}

// ---------------- shared helpers for SG GEMMs ----------------
#define KP 36  // padded row length (floats) for K=32 tiles: breaks bank-wrap
__device__ __forceinline__ int swzcol(int d, int k) {
  return (k & 3) | ((((unsigned(k) >> 2) ^ (unsigned(d) >> 2)) & 7) << 2);
}

// X: [DR][KP] swizzled LDS; WT: [>=DR][O] global; wch: [CH][O] LDS staging.
// ac must be pre-initialized by the caller (accumulates).
template <int DR, int O, int NT, int CH>
__device__ __forceinline__ void sg_gemm(const float* __restrict__ X,
                                        const float* __restrict__ WT,
                                        float* __restrict__ wch, int t, int o0, int kq,
                                        float (&ac)[4][4]) {
  for (int dc = 0; dc < DR; dc += CH) {
    __syncthreads();
    for (int i = t; i < CH * O; i += NT) wch[i] = WT[(size_t)dc * O + i];
    __syncthreads();
#pragma unroll 8
    for (int dd = 0; dd < CH; ++dd) {
      int d = dc + dd;
      const float4 wvv = *(const float4*)&wch[dd * O + o0];
      const float4 av = *(const float4*)&X[d * KP + ((kq ^ ((d >> 2) & 7)) << 2)];
      ac[0][0] += wvv.x * av.x; ac[0][1] += wvv.x * av.y; ac[0][2] += wvv.x * av.z; ac[0][3] += wvv.x * av.w;
      ac[1][0] += wvv.y * av.x; ac[1][1] += wvv.y * av.y; ac[1][2] += wvv.y * av.z; ac[1][3] += wvv.y * av.w;
      ac[2][0] += wvv.z * av.x; ac[2][1] += wvv.z * av.y; ac[2][2] += wvv.z * av.z; ac[2][3] += wvv.z * av.w;
      ac[3][0] += wvv.w * av.x; ac[3][1] += wvv.w * av.y; ac[3][2] += wvv.w * av.z; ac[3][3] += wvv.w * av.w;
    }
  }
}

// gather raw neighbor features V (D rows) into swizzled LDS, float4 granularity
template <int D, int NT>
__device__ __forceinline__ void sg_gatherV(const float* __restrict__ f, int Nf, int b,
                                           const int* __restrict__ nidx,
                                           float* __restrict__ V, int t) {
  constexpr int K = 32, DQ = D / 4;
  const float4* f4 = (const float4*)f;
  for (int idx = t; idx < K * DQ; idx += NT) {
    int k = idx / DQ, dq = idx - k * DQ;
    float4 v = f4[((size_t)b * Nf + nidx[k]) * DQ + dq];
    int d0 = dq * 4;
    V[(d0 + 0) * KP + swzcol(d0 + 0, k)] = v.x;
    V[(d0 + 1) * KP + swzcol(d0 + 1, k)] = v.y;
    V[(d0 + 2) * KP + swzcol(d0 + 2, k)] = v.z;
    V[(d0 + 3) * KP + swzcol(d0 + 3, k)] = v.w;
  }
}

// per-thread correction c[i2] = sum_d WdT[d][o0+i2] * q[d], reduced over kq-groups
template <int D, int O>
__device__ __forceinline__ void sg_corr(const float* __restrict__ WdT,
                                        const float* __restrict__ fqs, int o0, int kq,
                                        float (&c)[4]) {
  c[0] = c[1] = c[2] = c[3] = 0.f;
  for (int d = kq * (D / 8); d < (kq + 1) * (D / 8); ++d) {
    float qv = fqs[d];
    float4 wd = *(const float4*)&WdT[(size_t)d * O + o0];
    c[0] += wd.x * qv; c[1] += wd.y * qv; c[2] += wd.z * qv; c[3] += wd.w * qv;
  }
#pragma unroll
  for (int m = 1; m < 8; m <<= 1) {
    c[0] += __shfl_xor(c[0], m);
    c[1] += __shfl_xor(c[1], m);
    c[2] += __shfl_xor(c[2], m);
    c[3] += __shfl_xor(c[3], m);
  }
}

// ---------------- pass A: gather + split GEMM A -> statsA only ----------------
template <int D, int NT>
__global__ __launch_bounds__(NT) void k_sgA(const float* __restrict__ f, int Nf, int S,
                                            const int* __restrict__ fpsidx,
                                            const int* __restrict__ knn,
                                            const float* __restrict__ waT,
                                            const float* __restrict__ WdT,
                                            float* __restrict__ statsOut) {
  constexpr int D2 = 2 * D, O = D2, K = 32, CH = 16, DQ = D / 4;
  __shared__ __align__(16) float V[D * KP];
  __shared__ __align__(16) float wch[CH * O];
  __shared__ __align__(16) float fqs[D];
  __shared__ int nidx[K];
  __shared__ float red[2 * O];
  const int t = threadIdx.x;
  const int bs = blockIdx.x;
  const int b = bs / S;
  const int qi = fpsidx[bs];
  if (t < K) nidx[t] = knn[(size_t)bs * K + t];
  const float4* f4 = (const float4*)f;
  for (int i = t; i < DQ; i += NT)
    ((float4*)fqs)[i] = f4[((size_t)b * Nf + qi) * DQ + i];
  __syncthreads();
  sg_gatherV<D, NT>(f, Nf, b, nidx, V, t);
  const int oq = t >> 3, kq = t & 7;
  const int o0 = oq * 4;
  float c[4];
  sg_corr<D, O>(WdT, fqs, o0, kq, c);
  float acc[4][4];
#pragma unroll
  for (int i2 = 0; i2 < 4; ++i2)
#pragma unroll
    for (int j = 0; j < 4; ++j) acc[i2][j] = c[i2];
  sg_gemm<D, O, NT, CH>(V, waT, wch, t, o0, kq, acc);  // 1st barrier covers gather
#pragma unroll
  for (int i2 = 0; i2 < 4; ++i2) {
    float sv = acc[i2][0] + acc[i2][1] + acc[i2][2] + acc[i2][3];
    float sq = acc[i2][0] * acc[i2][0] + acc[i2][1] * acc[i2][1] +
               acc[i2][2] * acc[i2][2] + acc[i2][3] * acc[i2][3];
#pragma unroll
    for (int m = 1; m < 8; m <<= 1) {
      sv += __shfl_xor(sv, m);
      sq += __shfl_xor(sq, m);
    }
    if (kq == 0) {
      red[o0 + i2] = sv;
      red[O + o0 + i2] = sq;
    }
  }
  __syncthreads();
  float* slot = statsOut + (size_t)(bs & 63) * (2 * O);
  for (int i = t; i < 2 * O; i += NT) atomicAdd(&slot[i], red[i]);
}

// ------- pass AB: split A recompute, bnA+relu, GEMM B -> statsB + max/min yB -------
template <int D, int NT>
__global__ __launch_bounds__(NT) void k_sgAB(const float* __restrict__ f, int Nf, int S,
                                             const int* __restrict__ fpsidx,
                                             const int* __restrict__ knn,
                                             const float* __restrict__ waT,
                                             const float* __restrict__ WdT,
                                             const float* __restrict__ wbT,
                                             const float* __restrict__ bnA,
                                             float* __restrict__ statsOut,
                                             float* __restrict__ mm) {
  constexpr int D2 = 2 * D, O = D2, K = 32, CH = 16, DQ = D / 4;
  __shared__ __align__(16) float V[D * KP];
  __shared__ __align__(16) float zb[O * KP];
  __shared__ __align__(16) float wch[CH * O];
  __shared__ __align__(16) float fqs[D];
  __shared__ int nidx[K];
  __shared__ float red[2 * O];
  __shared__ float scb[2 * O];
  const int t = threadIdx.x;
  const int bs = blockIdx.x;
  const int b = bs / S;
  const int qi = fpsidx[bs];
  if (t < K) nidx[t] = knn[(size_t)bs * K + t];
  const float4* f4 = (const float4*)f;
  for (int i = t; i < DQ; i += NT)
    ((float4*)fqs)[i] = f4[((size_t)b * Nf + qi) * DQ + i];
  for (int i = t; i < 2 * O; i += NT) scb[i] = bnA[i];
  __syncthreads();
  sg_gatherV<D, NT>(f, Nf, b, nidx, V, t);
  const int oq = t >> 3, kq = t & 7;
  const int o0 = oq * 4;
  float c[4];
  sg_corr<D, O>(WdT, fqs, o0, kq, c);
  float acc[4][4];
#pragma unroll
  for (int i2 = 0; i2 < 4; ++i2)
#pragma unroll
    for (int j = 0; j < 4; ++j) acc[i2][j] = c[i2];
  sg_gemm<D, O, NT, CH>(V, waT, wch, t, o0, kq, acc);
  // zA = relu(bnA(yA)) into zb (conflict-free float4 writes)
#pragma unroll
  for (int i2 = 0; i2 < 4; ++i2) {
    float sA = scb[o0 + i2], tA = scb[O + o0 + i2];
    float4 z;
    z.x = fmaxf(0.f, acc[i2][0] * sA + tA);
    z.y = fmaxf(0.f, acc[i2][1] * sA + tA);
    z.z = fmaxf(0.f, acc[i2][2] * sA + tA);
    z.w = fmaxf(0.f, acc[i2][3] * sA + tA);
    *(float4*)&zb[(o0 + i2) * KP + ((kq ^ (oq & 7)) << 2)] = z;
  }
  float ac2[4][4];
#pragma unroll
  for (int i2 = 0; i2 < 4; ++i2)
#pragma unroll
    for (int j = 0; j < 4; ++j) ac2[i2][j] = 0.f;
  sg_gemm<O, O, NT, CH>(zb, wbT, wch, t, o0, kq, ac2);  // 1st barrier covers zb writes
  // statsB + max/min via 8-lane shuffle groups
  float* mrow = mm + (size_t)bs * 2 * O;
#pragma unroll
  for (int i2 = 0; i2 < 4; ++i2) {
    float sv = ac2[i2][0] + ac2[i2][1] + ac2[i2][2] + ac2[i2][3];
    float sq = ac2[i2][0] * ac2[i2][0] + ac2[i2][1] * ac2[i2][1] +
               ac2[i2][2] * ac2[i2][2] + ac2[i2][3] * ac2[i2][3];
    float mx = fmaxf(fmaxf(ac2[i2][0], ac2[i2][1]), fmaxf(ac2[i2][2], ac2[i2][3]));
    float mn = fminf(fminf(ac2[i2][0], ac2[i2][1]), fminf(ac2[i2][2], ac2[i2][3]));
#pragma unroll
    for (int m = 1; m < 8; m <<= 1) {
      sv += __shfl_xor(sv, m);
      sq += __shfl_xor(sq, m);
      mx = fmaxf(mx, __shfl_xor(mx, m));
      mn = fminf(mn, __shfl_xor(mn, m));
    }
    if (kq == 0) {
      red[o0 + i2] = sv;
      red[O + o0 + i2] = sq;
      mrow[o0 + i2] = mx;
      mrow[O + o0 + i2] = mn;
    }
  }
  __syncthreads();
  float* slot = statsOut + (size_t)(bs & 63) * (2 * O);
  for (int i = t; i < 2 * O; i += NT) atomicAdd(&slot[i], red[i]);
}

// ------- finalize: out = relu(sB * (sB>=0 ? maxYB : minYB) + tB) ------------------
template <int O>
__global__ __launch_bounds__(256) void k_fin(const float* __restrict__ mm,
                                             const float* __restrict__ bnB, int S,
                                             float* __restrict__ out, int finalOut) {
  int idx = blockIdx.x * 256 + threadIdx.x;
  int o, bs;
  if (finalOut) {
    int s = idx % S;
    int bo = idx / S;
    o = bo % O;
    int b = bo / O;
    bs = b * S + s;
  } else {
    o = idx % O;
    bs = idx / O;
  }
  float sB = bnB[o], tB = bnB[O + o];
  const float* r = mm + (size_t)bs * 2 * O;
  float ext = (sB >= 0.f) ? r[o] : r[O + o];
  out[idx] = fmaxf(0.f, sB * ext + tB);
}

// ---------------- host launch ----------------
extern "C" void kernel_launch(void* const* d_in, const int* in_sizes, int n_in,
                              void* d_out, int out_size, void* d_ws, size_t ws_size,
                              hipStream_t stream) {
  (void)in_sizes; (void)n_in; (void)out_size; (void)ws_size;
  const float* x    = (const float*)d_in[0];
  const float* w1   = (const float*)d_in[1];
  const float* g1   = (const float*)d_in[2];
  const float* b1   = (const float*)d_in[3];
  const float* w2   = (const float*)d_in[4];
  const float* g2   = (const float*)d_in[5];
  const float* b2   = (const float*)d_in[6];
  const float* s1wa = (const float*)d_in[7];
  const float* s1ga = (const float*)d_in[8];
  const float* s1ba = (const float*)d_in[9];
  const float* s1wb = (const float*)d_in[10];
  const float* s1gb = (const float*)d_in[11];
  const float* s1bb = (const float*)d_in[12];
  const float* s2wa = (const float*)d_in[13];
  const float* s2ga = (const float*)d_in[14];
  const float* s2ba = (const float*)d_in[15];
  const float* s2wb = (const float*)d_in[16];
  const float* s2gb = (const float*)d_in[17];
  const float* s2bb = (const float*)d_in[18];
  float* out = (float*)d_out;

  char* wsp = (char*)d_ws;
  size_t off = 0;
  auto alloc = [&](size_t floats) {
    void* p = wsp + off;
    off += ((floats * 4 + 255) & ~(size_t)255);
    return p;
  };
  float* xyz  = (float*)alloc(786432);     // [B][N][3]
  float* y1   = (float*)alloc(16777216);   // [B*N][64] conv1 raw -> conv2 in-place
  float* y2f  = y1;                        // alias (k_s1c tile-in-LDS then overwrite: safe)
  float* f1f  = (float*)alloc(2097152);    // [B][S1][128]
  float* xyz1 = (float*)alloc(49152);      // [B][S1][3]
  float* xyz2 = (float*)alloc(24576);      // [B][S2][3]
  int* fi1    = (int*)alloc(16384);        // [B][S1]
  int* fi2    = (int*)alloc(8192);         // [B][S2]
  int* kn1    = (int*)alloc(524288);       // [B][S1][32]
  int* kn2    = (int*)alloc(262144);       // [B][S2][32]
  float* w2T  = (float*)alloc(4096);
  float* waT1 = (float*)alloc(16384);
  float* wbT1 = (float*)alloc(16384);
  float* waT2 = (float*)alloc(65536);
  float* wbT2 = (float*)alloc(65536);
  float* WdT1 = (float*)alloc(8192);       // [64][128]
  float* WdT2 = (float*)alloc(32768);      // [128][256]
  float* stats = (float*)alloc(116480);
  float* part_s1 = stats;                  // [64][128]
  float* part_s2 = stats + 8192;
  float* partA1  = stats + 16384;          // [64][256]
  float* partB1  = stats + 32768;
  float* partA2  = stats + 49152;          // [64][512]
  float* partB2  = stats + 81920;
  float* sc1  = stats + 114688;            // [2*64]
  float* sc2  = sc1 + 128;
  float* bnA1 = sc2 + 128;                 // [2*128]
  float* bnB1 = bnA1 + 256;
  float* bnA2 = bnB1 + 256;                // [2*256]
  float* bnB2 = bnA2 + 512;
  // per-(bs,o) max/min of yB: max(16384*256, 8192*512) = 4,194,304 floats (16 MB)
  float* mm = (float*)alloc(4194304);

  hipMemsetAsync(stats, 0, (size_t)114688 * 4, stream);

  // weight transposes + split-correction weights
  k_transpose<<<(64 * 64 + 255) / 256, 256, 0, stream>>>(w2, w2T, 64, 64);
  k_transpose<<<(128 * 128 + 255) / 256, 256, 0, stream>>>(s1wa, waT1, 128, 128);
  k_transpose<<<(128 * 128 + 255) / 256, 256, 0, stream>>>(s1wb, wbT1, 128, 128);
  k_transpose<<<(256 * 256 + 255) / 256, 256, 0, stream>>>(s2wa, waT2, 256, 256);
  k_transpose<<<(256 * 256 + 255) / 256, 256, 0, stream>>>(s2wb, wbT2, 256, 256);
  k_wdiff<<<(64 * 128 + 255) / 256, 256, 0, stream>>>(s1wa, WdT1, 128, 64);
  k_wdiff<<<(128 * 256 + 255) / 256, 256, 0, stream>>>(s2wa, WdT2, 256, 128);

  const size_t MN = (size_t)NB * NP;  // 262144
  // stage 1
  k_s1a<<<(int)(MN / 256), 256, 0, stream>>>(x, w1, xyz, y1);
  k_colstats<<<1024, 256, 0, stream>>>(y1, MN * 16, part_s1);
  k_bnfinal<<<1, 64, 0, stream>>>(part_s1, g1, b1, 1.f / (float)MN, 64, sc1);
  k_s1c<<<(int)(MN / 64), 256, 0, stream>>>(y1, w2T, sc1, y2f);
  k_colstats<<<1024, 256, 0, stream>>>(y2f, MN * 16, part_s2);
  k_bnfinal<<<1, 64, 0, stream>>>(part_s2, g2, b2, 1.f / (float)MN, 64, sc2);
  k_s1e<<<2048, 256, 0, stream>>>(y2f, sc2, MN * 16);

  // sampling/grouping indices
  k_fps<NP, 512, 16><<<NB, 512, 0, stream>>>(xyz, fi1, xyz1);
  k_knn<32><<<NB * 512, 256, 0, stream>>>(xyz, xyz1, 512, kn1);

  const float icA1 = 1.f / (32.f * 512.f * 32.f);
  const float icA2 = 1.f / (32.f * 256.f * 32.f);

  // ---- SG block 1: A(stats) -> AB(stats+minmax) -> finalize ----
  k_sgA<64, 256><<<NB * 512, 256, 0, stream>>>(y2f, NP, 512, fi1, kn1, waT1, WdT1, partA1);
  k_bnfinal<<<1, 128, 0, stream>>>(partA1, s1ga, s1ba, icA1, 128, bnA1);
  k_sgAB<64, 256><<<NB * 512, 256, 0, stream>>>(y2f, NP, 512, fi1, kn1, waT1, WdT1,
                                                wbT1, bnA1, partB1, mm);
  k_bnfinal<<<1, 128, 0, stream>>>(partB1, s1gb, s1bb, icA1, 128, bnB1);
  k_fin<128><<<8192, 256, 0, stream>>>(mm, bnB1, 512, f1f, 0);

  k_fps<512, 256, 1><<<NB, 512, 0, stream>>>(xyz1, fi2, xyz2);
  k_knn<2><<<NB * 256, 256, 0, stream>>>(xyz1, xyz2, 256, kn2);

  // ---- SG block 2 ----
  k_sgA<128, 512><<<NB * 256, 512, 0, stream>>>(f1f, 512, 256, fi2, kn2, waT2, WdT2, partA2);
  k_bnfinal<<<1, 256, 0, stream>>>(partA2, s2ga, s2ba, icA2, 256, bnA2);
  k_sgAB<128, 512><<<NB * 256, 512, 0, stream>>>(f1f, 512, 256, fi2, kn2, waT2, WdT2,
                                                 wbT2, bnA2, partB2, mm);
  k_bnfinal<<<1, 256, 0, stream>>>(partB2, s2gb, s2bb, icA2, 256, bnB2);
  k_fin<256><<<8192, 256, 0, stream>>>(mm, bnB2, 256, out, 1);
}

// Round 9
// 4252.728 us; speedup vs baseline: 2.2185x; 1.0217x over previous
//
#include <hip/hip_runtime.h>
#include <hip/hip_bf16.h>

// ---------------- constants ----------------
// B=32, N=8192, S1=512, S2=256, K=32
#define NB 32
#define NP 8192

// ---------- distance helpers (match numpy: no FMA contraction) ----------
__device__ __forceinline__ float dist3(float ax, float ay, float az,
                                       float bx, float by, float bz) {
#pragma clang fp contract(off)
  float dx = ax - bx, dy = ay - by, dz = az - bz;
  return dx * dx + dy * dy + dz * dz;
}
__device__ __forceinline__ float sumsq3(float x, float y, float z) {
#pragma clang fp contract(off)
  return x * x + y * y + z * z;
}
__device__ __forceinline__ float knndist(float qx, float qy, float qz, float qq,
                                         float cx, float cy, float cz) {
#pragma clang fp contract(off)
  float dot = qx * cx + qy * cy + qz * cz;
  float cc = cx * cx + cy * cy + cz * cz;
  return (qq - 2.0f * dot) + cc;
}

// ---------------- weight transpose: wT[d][O] = w[o][d] ----------------
__global__ void k_transpose(const float* __restrict__ w, float* __restrict__ wT,
                            int O, int Dd) {
  int i = blockIdx.x * 256 + threadIdx.x;
  if (i < O * Dd) {
    int o = i / Dd, d = i - o * Dd;
    wT[d * O + o] = w[i];
  }
}

// ---------------- WdT[d][o] = w[o][D+d] - w[o][d]  (d < D, split correction) -------
__global__ void k_wdiff(const float* __restrict__ w, float* __restrict__ WdT,
                        int O, int D) {
  int i = blockIdx.x * 256 + threadIdx.x;
  if (i < D * O) {
    int d = i / O, o = i - d * O;
    WdT[i] = w[o * 2 * D + D + d] - w[o * 2 * D + d];
  }
}

// ---------------- stage1a: xyz + y1 = x * w1^T ----------------
__global__ __launch_bounds__(256) void k_s1a(const float* __restrict__ x,
                                             const float* __restrict__ w1,
                                             float* __restrict__ xyz,
                                             float* __restrict__ y1) {
  __shared__ float w1s[192];
  int t = threadIdx.x;
  if (t < 192) w1s[t] = w1[t];
  int gid = blockIdx.x * 256 + t;  // 0 .. B*N-1
  int b = gid >> 13, n = gid & (NP - 1);
  __syncthreads();
  const size_t xb = (size_t)b * 3 * NP;
  float x0 = x[xb + n], x1 = x[xb + NP + n], x2 = x[xb + 2 * NP + n];
  xyz[(size_t)gid * 3 + 0] = x0;
  xyz[(size_t)gid * 3 + 1] = x1;
  xyz[(size_t)gid * 3 + 2] = x2;
  float* yo = y1 + (size_t)gid * 64;
#pragma unroll
  for (int o = 0; o < 64; o += 4) {
    float4 v;
    v.x = x0 * w1s[(o + 0) * 3] + x1 * w1s[(o + 0) * 3 + 1] + x2 * w1s[(o + 0) * 3 + 2];
    v.y = x0 * w1s[(o + 1) * 3] + x1 * w1s[(o + 1) * 3 + 1] + x2 * w1s[(o + 1) * 3 + 2];
    v.z = x0 * w1s[(o + 2) * 3] + x1 * w1s[(o + 2) * 3 + 1] + x2 * w1s[(o + 2) * 3 + 2];
    v.w = x0 * w1s[(o + 3) * 3] + x1 * w1s[(o + 3) * 3 + 1] + x2 * w1s[(o + 3) * 3 + 2];
    *(float4*)&yo[o] = v;
  }
}

// ---------------- per-channel (C=64) sum/sumsq over [M][64], float4 ----------------
__global__ __launch_bounds__(256) void k_colstats(const float* __restrict__ buf,
                                                  size_t ME4, float* __restrict__ part) {
  __shared__ float red[128];
  int t = threadIdx.x;
  if (t < 128) red[t] = 0.f;
  float s[4] = {0.f, 0.f, 0.f, 0.f}, q[4] = {0.f, 0.f, 0.f, 0.f};
  size_t stride = (size_t)gridDim.x * 256;
  size_t i0 = (size_t)blockIdx.x * 256 + t;
  int c0 = (int)((i0 * 4) & 63);
  for (size_t i = i0; i < ME4; i += stride) {
    float4 v = ((const float4*)buf)[i];
    s[0] += v.x; q[0] += v.x * v.x;
    s[1] += v.y; q[1] += v.y * v.y;
    s[2] += v.z; q[2] += v.z * v.z;
    s[3] += v.w; q[3] += v.w * v.w;
  }
  __syncthreads();
#pragma unroll
  for (int j = 0; j < 4; ++j) {
    atomicAdd(&red[c0 + j], s[j]);
    atomicAdd(&red[64 + c0 + j], q[j]);
  }
  __syncthreads();
  if (t < 128) atomicAdd(&part[(size_t)(blockIdx.x & 63) * 128 + t], red[t]);
}

// ---------------- BN finalize: partials[P][2*C] -> scale/shift[2*C] ----------------
__global__ void k_bnfinal(const float* __restrict__ part, const float* __restrict__ gamma,
                          const float* __restrict__ beta, float invcnt, int C, int P,
                          float* __restrict__ sc) {
  int c = threadIdx.x;
  if (c >= C) return;
  float s = 0.f, q = 0.f;
  for (int p = 0; p < P; ++p) {
    s += part[(size_t)p * 2 * C + c];
    q += part[(size_t)p * 2 * C + C + c];
  }
  float mean = s * invcnt;
  float var = fmaxf(q * invcnt - mean * mean, 0.f);
  float scale = gamma[c] * rsqrtf(var + 1e-5f);
  sc[c] = scale;
  sc[C + c] = beta[c] - mean * scale;
}

// ---------------- stage1c: y2 = w2 * relu(bn(y1)), 64-point tiles (in-place safe) ----
__global__ __launch_bounds__(256) void k_s1c(const float* __restrict__ y1,
                                             const float* __restrict__ w2T,
                                             const float* __restrict__ sc1,
                                             float* __restrict__ y2) {
  __shared__ __align__(16) float f1[64 * 65];
  __shared__ __align__(16) float w2s[64 * 64];
  __shared__ float scs[128];
  int t = threadIdx.x;
  if (t < 128) scs[t] = sc1[t];
  for (int i = t; i < 4096; i += 256) w2s[i] = w2T[i];
  size_t base = (size_t)blockIdx.x * 4096;
  __syncthreads();
  for (int i = t; i < 4096; i += 256) {
    int p = i >> 6, c = i & 63;
    float v = y1[base + i];
    v = fmaxf(0.f, v * scs[c] + scs[64 + c]);
    f1[p * 65 + c] = v;
  }
  __syncthreads();
  int pq = t & 15, oq = t >> 4;
  int p0 = pq * 4, o0 = oq * 4;
  float ac[4][4] = {};
  for (int c = 0; c < 64; ++c) {
    float4 wv = *(const float4*)&w2s[c * 64 + o0];
    float a0 = f1[(p0 + 0) * 65 + c];
    float a1 = f1[(p0 + 1) * 65 + c];
    float a2 = f1[(p0 + 2) * 65 + c];
    float a3 = f1[(p0 + 3) * 65 + c];
    ac[0][0] += a0 * wv.x; ac[0][1] += a0 * wv.y; ac[0][2] += a0 * wv.z; ac[0][3] += a0 * wv.w;
    ac[1][0] += a1 * wv.x; ac[1][1] += a1 * wv.y; ac[1][2] += a1 * wv.z; ac[1][3] += a1 * wv.w;
    ac[2][0] += a2 * wv.x; ac[2][1] += a2 * wv.y; ac[2][2] += a2 * wv.z; ac[2][3] += a2 * wv.w;
    ac[3][0] += a3 * wv.x; ac[3][1] += a3 * wv.y; ac[3][2] += a3 * wv.z; ac[3][3] += a3 * wv.w;
  }
#pragma unroll
  for (int i2 = 0; i2 < 4; ++i2) {
    float4 v = {ac[i2][0], ac[i2][1], ac[i2][2], ac[i2][3]};
    *(float4*)&y2[base + (size_t)(p0 + i2) * 64 + o0] = v;
  }
}

// ---------------- stage1e: in-place bn+relu over [M][64] ----------------
__global__ __launch_bounds__(256) void k_s1e(float* __restrict__ y2,
                                             const float* __restrict__ sc2, size_t ME4) {
  __shared__ float scs[128];
  int t = threadIdx.x;
  if (t < 128) scs[t] = sc2[t];
  __syncthreads();
  size_t stride = (size_t)gridDim.x * 256;
  for (size_t i = (size_t)blockIdx.x * 256 + t; i < ME4; i += stride) {
    float4 v = ((float4*)y2)[i];
    int c0 = (int)((i * 4) & 63);
    v.x = fmaxf(0.f, v.x * scs[c0 + 0] + scs[64 + c0 + 0]);
    v.y = fmaxf(0.f, v.y * scs[c0 + 1] + scs[64 + c0 + 1]);
    v.z = fmaxf(0.f, v.z * scs[c0 + 2] + scs[64 + c0 + 2]);
    v.w = fmaxf(0.f, v.w * scs[c0 + 3] + scs[64 + c0 + 3]);
    ((float4*)y2)[i] = v;
  }
}

// ---------------- FPS: LDS-resident coords, 1 barrier/iter ----------------
template <int N, int S, int PPT>
__global__ __launch_bounds__(N / PPT) void k_fps(const float* __restrict__ xyz,
                                                 int* __restrict__ fidx,
                                                 float* __restrict__ sxyz) {
  constexpr int T = N / PPT;
  constexpr int NW = T / 64;
  __shared__ float cl[N * 3];
  __shared__ float wv[2][NW];
  __shared__ int wi[2][NW];
  const int t = threadIdx.x;
  const int b = blockIdx.x;
  const float* base = xyz + (size_t)b * N * 3;
  for (int i = t; i < 3 * N; i += T) cl[i] = base[i];
  __syncthreads();
  float cx[PPT], cy[PPT], cz[PPT], dist[PPT];
#pragma unroll
  for (int j = 0; j < PPT; ++j) {
    int n = t + j * T;
    cx[j] = cl[n * 3 + 0];
    cy[j] = cl[n * 3 + 1];
    cz[j] = cl[n * 3 + 2];
    dist[j] = 1e10f;
  }
  float px = cl[0], py = cl[1], pz = cl[2];
  if (t == 0) {
    fidx[(size_t)b * S] = 0;
    sxyz[(size_t)b * S * 3 + 0] = px;
    sxyz[(size_t)b * S * 3 + 1] = py;
    sxyz[(size_t)b * S * 3 + 2] = pz;
  }
  int par = 0;
  for (int it = 1; it < S; ++it) {
    float bv = -1.0f;
    int bi = 0x7FFFFFFF;
#pragma unroll
    for (int j = 0; j < PPT; ++j) {
      float d = dist3(cx[j], cy[j], cz[j], px, py, pz);
      float dj = fminf(dist[j], d);
      dist[j] = dj;
      if (dj > bv) { bv = dj; bi = t + j * T; }  // j asc -> first (smallest n) in thread
    }
#pragma unroll
    for (int off = 32; off > 0; off >>= 1) {
      float ov = __shfl_xor(bv, off);
      int oi = __shfl_xor(bi, off);
      if (ov > bv || (ov == bv && oi < bi)) { bv = ov; bi = oi; }
    }
    if ((t & 63) == 0) { wv[par][t >> 6] = bv; wi[par][t >> 6] = bi; }
    __syncthreads();
    float v = wv[par][0];
    int ii = wi[par][0];
#pragma unroll
    for (int w = 1; w < NW; ++w) {
      float ov = wv[par][w];
      int oi = wi[par][w];
      if (ov > v || (ov == v && oi < ii)) { v = ov; ii = oi; }
    }
    px = cl[ii * 3 + 0]; py = cl[ii * 3 + 1]; pz = cl[ii * 3 + 2];
    if (t == 0) {
      fidx[(size_t)b * S + it] = ii;
      sxyz[((size_t)b * S + it) * 3 + 0] = px;
      sxyz[((size_t)b * S + it) * 3 + 1] = py;
      sxyz[((size_t)b * S + it) * 3 + 2] = pz;
    }
    par ^= 1;
  }
}

// ---------------- FPS single-wave variant (no barriers in the loop) ----------------
template <int N, int S, int PPT>
__global__ __launch_bounds__(64) void k_fpsw(const float* __restrict__ xyz,
                                             int* __restrict__ fidx,
                                             float* __restrict__ sxyz) {
  __shared__ float cl[N * 3];
  const int t = threadIdx.x;
  const int b = blockIdx.x;
  const float* base = xyz + (size_t)b * N * 3;
  for (int i = t; i < 3 * N; i += 64) cl[i] = base[i];
  __syncthreads();  // single wave: compiles to waitcnt+barrier, ensures LDS visible
  float cx[PPT], cy[PPT], cz[PPT], dist[PPT];
#pragma unroll
  for (int j = 0; j < PPT; ++j) {
    int n = t + j * 64;
    cx[j] = cl[n * 3 + 0];
    cy[j] = cl[n * 3 + 1];
    cz[j] = cl[n * 3 + 2];
    dist[j] = 1e10f;
  }
  float px = cl[0], py = cl[1], pz = cl[2];
  if (t == 0) {
    fidx[(size_t)b * S] = 0;
    sxyz[(size_t)b * S * 3 + 0] = px;
    sxyz[(size_t)b * S * 3 + 1] = py;
    sxyz[(size_t)b * S * 3 + 2] = pz;
  }
  for (int it = 1; it < S; ++it) {
    float bv = -1.0f;
    int bi = 0x7FFFFFFF;
#pragma unroll
    for (int j = 0; j < PPT; ++j) {
      float d = dist3(cx[j], cy[j], cz[j], px, py, pz);
      float dj = fminf(dist[j], d);
      dist[j] = dj;
      if (dj > bv) { bv = dj; bi = t + j * 64; }
    }
#pragma unroll
    for (int off = 32; off > 0; off >>= 1) {
      float ov = __shfl_xor(bv, off);
      int oi = __shfl_xor(bi, off);
      if (ov > bv || (ov == bv && oi < bi)) { bv = ov; bi = oi; }
    }
    // all 64 lanes now hold the winner (bv,bi); cl is read-only
    px = cl[bi * 3 + 0]; py = cl[bi * 3 + 1]; pz = cl[bi * 3 + 2];
    if (t == 0) {
      fidx[(size_t)b * S + it] = bi;
      sxyz[((size_t)b * S + it) * 3 + 0] = px;
      sxyz[((size_t)b * S + it) * 3 + 1] = py;
      sxyz[((size_t)b * S + it) * 3 + 2] = pz;
    }
  }
}

// ---------------- KNN top-32: register candidates + incremental local min ----------
template <int NPT>
__global__ __launch_bounds__(256) void k_knn(const float* __restrict__ cxyz,
                                             const float* __restrict__ qxyz, int S,
                                             int* __restrict__ knn) {
  constexpr int N = NPT * 256;
  __shared__ float wv[2][4];
  __shared__ int wi[2][4];
  const int t = threadIdx.x;
  const int bs = blockIdx.x;
  const int b = bs / S;
  float qx = qxyz[(size_t)bs * 3 + 0];
  float qy = qxyz[(size_t)bs * 3 + 1];
  float qz = qxyz[(size_t)bs * 3 + 2];
  float qq = sumsq3(qx, qy, qz);
  const float* cb = cxyz + (size_t)b * N * 3;
  float ds[NPT];
  float lmin = 3.0e38f;
  int li = 0x7FFFFFFF;
#pragma unroll
  for (int j = 0; j < NPT; ++j) {
    int n = t + j * 256;
    float d = knndist(qx, qy, qz, qq, cb[(size_t)n * 3], cb[(size_t)n * 3 + 1],
                      cb[(size_t)n * 3 + 2]);
    ds[j] = d;
    if (d < lmin) { lmin = d; li = n; }
  }
  int par = 0;
  for (int r = 0; r < 32; ++r) {
    float bv = lmin;
    int bi = li;
#pragma unroll
    for (int off = 32; off > 0; off >>= 1) {
      float ov = __shfl_xor(bv, off);
      int oi = __shfl_xor(bi, off);
      if (ov < bv || (ov == bv && oi < bi)) { bv = ov; bi = oi; }
    }
    if ((t & 63) == 0) { wv[par][t >> 6] = bv; wi[par][t >> 6] = bi; }
    __syncthreads();
    float v = wv[par][0];
    int ii = wi[par][0];
#pragma unroll
    for (int w = 1; w < 4; ++w) {
      float ov = wv[par][w];
      int oi = wi[par][w];
      if (ov < v || (ov == v && oi < ii)) { v = ov; ii = oi; }
    }
    if (t == 0) knn[(size_t)bs * 32 + r] = ii;
    if (li == ii) {  // only the owner rescans
#pragma unroll
      for (int j = 0; j < NPT; ++j)
        if (t + j * 256 == ii) ds[j] = 3.0e38f;
      lmin = 3.0e38f;
      li = 0x7FFFFFFF;
#pragma unroll
      for (int j = 0; j < NPT; ++j)
        if (ds[j] < lmin) { lmin = ds[j]; li = t + j * 256; }
    }
    par ^= 1;
  }
}

// ---------------- shared helpers for SG GEMMs ----------------
#define KP 36  // padded row length (floats) for K=32 tiles: breaks bank-wrap
__device__ __forceinline__ int swzcol(int d, int k) {
  return (k & 3) | ((((unsigned(k) >> 2) ^ (unsigned(d) >> 2)) & 7) << 2);
}

// X: [DR][KP] swizzled LDS; WT: [>=DR][O] global; wch: [CH][O] LDS staging.
// ac must be pre-initialized by the caller (accumulates).
template <int DR, int O, int NT, int CH>
__device__ __forceinline__ void sg_gemm(const float* __restrict__ X,
                                        const float* __restrict__ WT,
                                        float* __restrict__ wch, int t, int o0, int kq,
                                        float (&ac)[4][4]) {
  for (int dc = 0; dc < DR; dc += CH) {
    __syncthreads();
    for (int i = t; i < CH * O; i += NT) wch[i] = WT[(size_t)dc * O + i];
    __syncthreads();
#pragma unroll 8
    for (int dd = 0; dd < CH; ++dd) {
      int d = dc + dd;
      const float4 wvv = *(const float4*)&wch[dd * O + o0];
      const float4 av = *(const float4*)&X[d * KP + ((kq ^ ((d >> 2) & 7)) << 2)];
      ac[0][0] += wvv.x * av.x; ac[0][1] += wvv.x * av.y; ac[0][2] += wvv.x * av.z; ac[0][3] += wvv.x * av.w;
      ac[1][0] += wvv.y * av.x; ac[1][1] += wvv.y * av.y; ac[1][2] += wvv.y * av.z; ac[1][3] += wvv.y * av.w;
      ac[2][0] += wvv.z * av.x; ac[2][1] += wvv.z * av.y; ac[2][2] += wvv.z * av.z; ac[2][3] += wvv.z * av.w;
      ac[3][0] += wvv.w * av.x; ac[3][1] += wvv.w * av.y; ac[3][2] += wvv.w * av.z; ac[3][3] += wvv.w * av.w;
    }
  }
}

// gather raw neighbor features V (D rows) into swizzled LDS, float4 granularity
template <int D, int NT>
__device__ __forceinline__ void sg_gatherV(const float* __restrict__ f, int Nf, int b,
                                           const int* __restrict__ nidx,
                                           float* __restrict__ V, int t) {
  constexpr int K = 32, DQ = D / 4;
  const float4* f4 = (const float4*)f;
  for (int idx = t; idx < K * DQ; idx += NT) {
    int k = idx / DQ, dq = idx - k * DQ;
    float4 v = f4[((size_t)b * Nf + nidx[k]) * DQ + dq];
    int d0 = dq * 4;
    V[(d0 + 0) * KP + swzcol(d0 + 0, k)] = v.x;
    V[(d0 + 1) * KP + swzcol(d0 + 1, k)] = v.y;
    V[(d0 + 2) * KP + swzcol(d0 + 2, k)] = v.z;
    V[(d0 + 3) * KP + swzcol(d0 + 3, k)] = v.w;
  }
}

// per-thread correction c[i2] = sum_d WdT[d][o0+i2] * q[d], reduced over kq-groups
template <int D, int O>
__device__ __forceinline__ void sg_corr(const float* __restrict__ WdT,
                                        const float* __restrict__ fqs, int o0, int kq,
                                        float (&c)[4]) {
  c[0] = c[1] = c[2] = c[3] = 0.f;
  for (int d = kq * (D / 8); d < (kq + 1) * (D / 8); ++d) {
    float qv = fqs[d];
    float4 wd = *(const float4*)&WdT[(size_t)d * O + o0];
    c[0] += wd.x * qv; c[1] += wd.y * qv; c[2] += wd.z * qv; c[3] += wd.w * qv;
  }
#pragma unroll
  for (int m = 1; m < 8; m <<= 1) {
    c[0] += __shfl_xor(c[0], m);
    c[1] += __shfl_xor(c[1], m);
    c[2] += __shfl_xor(c[2], m);
    c[3] += __shfl_xor(c[3], m);
  }
}

// ---------------- pass A: gather + split GEMM A -> statsA only ----------------
template <int D, int NT>
__global__ __launch_bounds__(NT) void k_sgA(const float* __restrict__ f, int Nf, int S,
                                            const int* __restrict__ fpsidx,
                                            const int* __restrict__ knn,
                                            const float* __restrict__ waT,
                                            const float* __restrict__ WdT,
                                            float* __restrict__ statsOut) {
  constexpr int D2 = 2 * D, O = D2, K = 32, CH = 16, DQ = D / 4;
  __shared__ __align__(16) float V[D * KP];
  __shared__ __align__(16) float wch[CH * O];
  __shared__ __align__(16) float fqs[D];
  __shared__ int nidx[K];
  __shared__ float red[2 * O];
  const int t = threadIdx.x;
  const int bs = blockIdx.x;
  const int b = bs / S;
  const int qi = fpsidx[bs];
  if (t < K) nidx[t] = knn[(size_t)bs * K + t];
  const float4* f4 = (const float4*)f;
  for (int i = t; i < DQ; i += NT)
    ((float4*)fqs)[i] = f4[((size_t)b * Nf + qi) * DQ + i];
  __syncthreads();
  sg_gatherV<D, NT>(f, Nf, b, nidx, V, t);
  const int oq = t >> 3, kq = t & 7;
  const int o0 = oq * 4;
  float c[4];
  sg_corr<D, O>(WdT, fqs, o0, kq, c);
  float acc[4][4];
#pragma unroll
  for (int i2 = 0; i2 < 4; ++i2)
#pragma unroll
    for (int j = 0; j < 4; ++j) acc[i2][j] = c[i2];
  sg_gemm<D, O, NT, CH>(V, waT, wch, t, o0, kq, acc);  // 1st barrier covers gather
#pragma unroll
  for (int i2 = 0; i2 < 4; ++i2) {
    float sv = acc[i2][0] + acc[i2][1] + acc[i2][2] + acc[i2][3];
    float sq = acc[i2][0] * acc[i2][0] + acc[i2][1] * acc[i2][1] +
               acc[i2][2] * acc[i2][2] + acc[i2][3] * acc[i2][3];
#pragma unroll
    for (int m = 1; m < 8; m <<= 1) {
      sv += __shfl_xor(sv, m);
      sq += __shfl_xor(sq, m);
    }
    if (kq == 0) {
      red[o0 + i2] = sv;
      red[O + o0 + i2] = sq;
    }
  }
  __syncthreads();
  float* slot = statsOut + (size_t)(bs & 255) * (2 * O);
  for (int i = t; i < 2 * O; i += NT) atomicAdd(&slot[i], red[i]);
}

// ------- pass AB: split A recompute, bnA+relu, GEMM B -> statsB + max/min yB -------
// zb aliases V's LDS (union): GEMM-B never reads V; barrier separates phases.
template <int D, int NT>
__global__ __launch_bounds__(NT) void k_sgAB(const float* __restrict__ f, int Nf, int S,
                                             const int* __restrict__ fpsidx,
                                             const int* __restrict__ knn,
                                             const float* __restrict__ waT,
                                             const float* __restrict__ WdT,
                                             const float* __restrict__ wbT,
                                             const float* __restrict__ bnA,
                                             float* __restrict__ statsOut,
                                             float* __restrict__ mm) {
  constexpr int D2 = 2 * D, O = D2, K = 32, CH = 32, DQ = D / 4;
  __shared__ __align__(16) float VZ[O * KP];  // V (rows 0..D-1) then reused as zb (O rows)
  __shared__ __align__(16) float wch[CH * O];
  __shared__ __align__(16) float fqs[D];
  __shared__ int nidx[K];
  __shared__ float red[2 * O];
  __shared__ float scb[2 * O];
  const int t = threadIdx.x;
  const int bs = blockIdx.x;
  const int b = bs / S;
  const int qi = fpsidx[bs];
  if (t < K) nidx[t] = knn[(size_t)bs * K + t];
  const float4* f4 = (const float4*)f;
  for (int i = t; i < DQ; i += NT)
    ((float4*)fqs)[i] = f4[((size_t)b * Nf + qi) * DQ + i];
  for (int i = t; i < 2 * O; i += NT) scb[i] = bnA[i];
  __syncthreads();
  sg_gatherV<D, NT>(f, Nf, b, nidx, VZ, t);
  const int oq = t >> 3, kq = t & 7;
  const int o0 = oq * 4;
  float c[4];
  sg_corr<D, O>(WdT, fqs, o0, kq, c);
  float acc[4][4];
#pragma unroll
  for (int i2 = 0; i2 < 4; ++i2)
#pragma unroll
    for (int j = 0; j < 4; ++j) acc[i2][j] = c[i2];
  sg_gemm<D, O, NT, CH>(VZ, waT, wch, t, o0, kq, acc);
  __syncthreads();  // all GEMM-A reads of VZ complete before zb overwrite
  // zA = relu(bnA(yA)) into VZ (conflict-free float4 writes)
#pragma unroll
  for (int i2 = 0; i2 < 4; ++i2) {
    float sA = scb[o0 + i2], tA = scb[O + o0 + i2];
    float4 z;
    z.x = fmaxf(0.f, acc[i2][0] * sA + tA);
    z.y = fmaxf(0.f, acc[i2][1] * sA + tA);
    z.z = fmaxf(0.f, acc[i2][2] * sA + tA);
    z.w = fmaxf(0.f, acc[i2][3] * sA + tA);
    *(float4*)&VZ[(o0 + i2) * KP + ((kq ^ (oq & 7)) << 2)] = z;
  }
  float ac2[4][4];
#pragma unroll
  for (int i2 = 0; i2 < 4; ++i2)
#pragma unroll
    for (int j = 0; j < 4; ++j) ac2[i2][j] = 0.f;
  sg_gemm<O, O, NT, CH>(VZ, wbT, wch, t, o0, kq, ac2);  // 1st barrier covers zb writes
  // statsB + max/min via 8-lane shuffle groups
  float* mrow = mm + (size_t)bs * 2 * O;
#pragma unroll
  for (int i2 = 0; i2 < 4; ++i2) {
    float sv = ac2[i2][0] + ac2[i2][1] + ac2[i2][2] + ac2[i2][3];
    float sq = ac2[i2][0] * ac2[i2][0] + ac2[i2][1] * ac2[i2][1] +
               ac2[i2][2] * ac2[i2][2] + ac2[i2][3] * ac2[i2][3];
    float mx = fmaxf(fmaxf(ac2[i2][0], ac2[i2][1]), fmaxf(ac2[i2][2], ac2[i2][3]));
    float mn = fminf(fminf(ac2[i2][0], ac2[i2][1]), fminf(ac2[i2][2], ac2[i2][3]));
#pragma unroll
    for (int m = 1; m < 8; m <<= 1) {
      sv += __shfl_xor(sv, m);
      sq += __shfl_xor(sq, m);
      mx = fmaxf(mx, __shfl_xor(mx, m));
      mn = fminf(mn, __shfl_xor(mn, m));
    }
    if (kq == 0) {
      red[o0 + i2] = sv;
      red[O + o0 + i2] = sq;
      mrow[o0 + i2] = mx;
      mrow[O + o0 + i2] = mn;
    }
  }
  __syncthreads();
  float* slot = statsOut + (size_t)(bs & 255) * (2 * O);
  for (int i = t; i < 2 * O; i += NT) atomicAdd(&slot[i], red[i]);
}

// ------- finalize: out = relu(sB * (sB>=0 ? maxYB : minYB) + tB) ------------------
template <int O>
__global__ __launch_bounds__(256) void k_fin(const float* __restrict__ mm,
                                             const float* __restrict__ bnB, int S,
                                             float* __restrict__ out, int finalOut) {
  int idx = blockIdx.x * 256 + threadIdx.x;
  int o, bs;
  if (finalOut) {
    int s = idx % S;
    int bo = idx / S;
    o = bo % O;
    int b = bo / O;
    bs = b * S + s;
  } else {
    o = idx % O;
    bs = idx / O;
  }
  float sB = bnB[o], tB = bnB[O + o];
  const float* r = mm + (size_t)bs * 2 * O;
  float ext = (sB >= 0.f) ? r[o] : r[O + o];
  out[idx] = fmaxf(0.f, sB * ext + tB);
}

// ---------------- host launch ----------------
extern "C" void kernel_launch(void* const* d_in, const int* in_sizes, int n_in,
                              void* d_out, int out_size, void* d_ws, size_t ws_size,
                              hipStream_t stream) {
  (void)in_sizes; (void)n_in; (void)out_size; (void)ws_size;
  const float* x    = (const float*)d_in[0];
  const float* w1   = (const float*)d_in[1];
  const float* g1   = (const float*)d_in[2];
  const float* b1   = (const float*)d_in[3];
  const float* w2   = (const float*)d_in[4];
  const float* g2   = (const float*)d_in[5];
  const float* b2   = (const float*)d_in[6];
  const float* s1wa = (const float*)d_in[7];
  const float* s1ga = (const float*)d_in[8];
  const float* s1ba = (const float*)d_in[9];
  const float* s1wb = (const float*)d_in[10];
  const float* s1gb = (const float*)d_in[11];
  const float* s1bb = (const float*)d_in[12];
  const float* s2wa = (const float*)d_in[13];
  const float* s2ga = (const float*)d_in[14];
  const float* s2ba = (const float*)d_in[15];
  const float* s2wb = (const float*)d_in[16];
  const float* s2gb = (const float*)d_in[17];
  const float* s2bb = (const float*)d_in[18];
  float* out = (float*)d_out;

  char* wsp = (char*)d_ws;
  size_t off = 0;
  auto alloc = [&](size_t floats) {
    void* p = wsp + off;
    off += ((floats * 4 + 255) & ~(size_t)255);
    return p;
  };
  float* xyz  = (float*)alloc(786432);     // [B][N][3]
  float* y1   = (float*)alloc(16777216);   // [B*N][64] conv1 raw -> conv2 in-place
  float* y2f  = y1;                        // alias (k_s1c tile-in-LDS then overwrite: safe)
  float* f1f  = (float*)alloc(2097152);    // [B][S1][128]
  float* xyz1 = (float*)alloc(49152);      // [B][S1][3]
  float* xyz2 = (float*)alloc(24576);      // [B][S2][3]
  int* fi1    = (int*)alloc(16384);        // [B][S1]
  int* fi2    = (int*)alloc(8192);         // [B][S2]
  int* kn1    = (int*)alloc(524288);       // [B][S1][32]
  int* kn2    = (int*)alloc(262144);       // [B][S2][32]
  float* w2T  = (float*)alloc(4096);
  float* waT1 = (float*)alloc(16384);
  float* wbT1 = (float*)alloc(16384);
  float* waT2 = (float*)alloc(65536);
  float* wbT2 = (float*)alloc(65536);
  float* WdT1 = (float*)alloc(8192);       // [64][128]
  float* WdT2 = (float*)alloc(32768);      // [128][256]
  float* stats = (float*)alloc(411392);
  float* part_s1 = stats;                  // [64][128]
  float* part_s2 = stats + 8192;           // [64][128]
  float* partA1  = stats + 16384;          // [256][256]
  float* partB1  = stats + 81920;          // [256][256]
  float* partA2  = stats + 147456;         // [256][512]
  float* partB2  = stats + 278528;         // [256][512]
  float* sc1  = stats + 409600;            // [2*64]
  float* sc2  = sc1 + 128;
  float* bnA1 = sc2 + 128;                 // [2*128]
  float* bnB1 = bnA1 + 256;
  float* bnA2 = bnB1 + 256;                // [2*256]
  float* bnB2 = bnA2 + 512;
  // per-(bs,o) max/min of yB: max(16384*256, 8192*512) = 4,194,304 floats (16 MB)
  float* mm = (float*)alloc(4194304);

  hipMemsetAsync(stats, 0, (size_t)409600 * 4, stream);

  // weight transposes + split-correction weights
  k_transpose<<<(64 * 64 + 255) / 256, 256, 0, stream>>>(w2, w2T, 64, 64);
  k_transpose<<<(128 * 128 + 255) / 256, 256, 0, stream>>>(s1wa, waT1, 128, 128);
  k_transpose<<<(128 * 128 + 255) / 256, 256, 0, stream>>>(s1wb, wbT1, 128, 128);
  k_transpose<<<(256 * 256 + 255) / 256, 256, 0, stream>>>(s2wa, waT2, 256, 256);
  k_transpose<<<(256 * 256 + 255) / 256, 256, 0, stream>>>(s2wb, wbT2, 256, 256);
  k_wdiff<<<(64 * 128 + 255) / 256, 256, 0, stream>>>(s1wa, WdT1, 128, 64);
  k_wdiff<<<(128 * 256 + 255) / 256, 256, 0, stream>>>(s2wa, WdT2, 256, 128);

  const size_t MN = (size_t)NB * NP;  // 262144
  // stage 1
  k_s1a<<<(int)(MN / 256), 256, 0, stream>>>(x, w1, xyz, y1);
  k_colstats<<<1024, 256, 0, stream>>>(y1, MN * 16, part_s1);
  k_bnfinal<<<1, 64, 0, stream>>>(part_s1, g1, b1, 1.f / (float)MN, 64, 64, sc1);
  k_s1c<<<(int)(MN / 64), 256, 0, stream>>>(y1, w2T, sc1, y2f);
  k_colstats<<<1024, 256, 0, stream>>>(y2f, MN * 16, part_s2);
  k_bnfinal<<<1, 64, 0, stream>>>(part_s2, g2, b2, 1.f / (float)MN, 64, 64, sc2);
  k_s1e<<<2048, 256, 0, stream>>>(y2f, sc2, MN * 16);

  // sampling/grouping indices
  k_fps<NP, 512, 32><<<NB, 256, 0, stream>>>(xyz, fi1, xyz1);
  k_knn<32><<<NB * 512, 256, 0, stream>>>(xyz, xyz1, 512, kn1);

  const float icA1 = 1.f / (32.f * 512.f * 32.f);
  const float icA2 = 1.f / (32.f * 256.f * 32.f);

  // ---- SG block 1: A(stats) -> AB(stats+minmax) -> finalize ----
  k_sgA<64, 256><<<NB * 512, 256, 0, stream>>>(y2f, NP, 512, fi1, kn1, waT1, WdT1, partA1);
  k_bnfinal<<<1, 128, 0, stream>>>(partA1, s1ga, s1ba, icA1, 128, 256, bnA1);
  k_sgAB<64, 256><<<NB * 512, 256, 0, stream>>>(y2f, NP, 512, fi1, kn1, waT1, WdT1,
                                                wbT1, bnA1, partB1, mm);
  k_bnfinal<<<1, 128, 0, stream>>>(partB1, s1gb, s1bb, icA1, 128, 256, bnB1);
  k_fin<128><<<8192, 256, 0, stream>>>(mm, bnB1, 512, f1f, 0);

  k_fpsw<512, 256, 8><<<NB, 64, 0, stream>>>(xyz1, fi2, xyz2);
  k_knn<2><<<NB * 256, 256, 0, stream>>>(xyz1, xyz2, 256, kn2);

  // ---- SG block 2 ----
  k_sgA<128, 512><<<NB * 256, 512, 0, stream>>>(f1f, 512, 256, fi2, kn2, waT2, WdT2, partA2);
  k_bnfinal<<<1, 256, 0, stream>>>(partA2, s2ga, s2ba, icA2, 256, 256, bnA2);
  k_sgAB<128, 512><<<NB * 256, 512, 0, stream>>>(f1f, 512, 256, fi2, kn2, waT2, WdT2,
                                                 wbT2, bnA2, partB2, mm);
  k_bnfinal<<<1, 256, 0, stream>>>(partB2, s2gb, s2bb, icA2, 256, 256, bnB2);
  k_fin<256><<<8192, 256, 0, stream>>>(mm, bnB2, 256, out, 1);
}